// Round 6
// baseline (1359.113 us; speedup 1.0000x reference)
//
#include <hip/hip_runtime.h>
#include <math.h>

#define BUCKET_SHIFT 8            // 256 nodes per bucket
#define BUCKET_MASK 255
#define MAXBUCK 640               // supports N <= 163840
#define TILE 8192

typedef __attribute__((ext_vector_type(8))) short bf16x8;
typedef __attribute__((ext_vector_type(4))) float f32x4;

__device__ inline float bf_lo(unsigned u) { return __uint_as_float(u << 16); }
__device__ inline float bf_hi(unsigned u) { return __uint_as_float(u & 0xffff0000u); }
__device__ inline unsigned short f2bf(float f) {   // round-to-nearest-even
  unsigned u = __float_as_uint(f);
  return (unsigned short)((u + 0x7fffu + ((u >> 16) & 1u)) >> 16);
}
__device__ inline void acc8(float* a, uint4 v) {
  a[0] += bf_lo(v.x); a[1] += bf_hi(v.x);
  a[2] += bf_lo(v.y); a[3] += bf_hi(v.y);
  a[4] += bf_lo(v.z); a[5] += bf_hi(v.z);
  a[6] += bf_lo(v.w); a[7] += bf_hi(v.w);
}

// ---------------- utility ----------------
__global__ void zero_u32(unsigned int* __restrict__ p, int n) {
  int i = blockIdx.x * blockDim.x + threadIdx.x;
  if (i < n) p[i] = 0u;
}

// ---------------- bucketed CSR build ----------------
__global__ __launch_bounds__(256) void bucket_count(const int* __restrict__ dst,
                                                    int* __restrict__ bcnt, int e, int nbuck) {
  __shared__ int lc[MAXBUCK];
  for (int i = threadIdx.x; i < nbuck; i += 256) lc[i] = 0;
  __syncthreads();
  for (int i = blockIdx.x * blockDim.x + threadIdx.x; i < e; i += gridDim.x * blockDim.x)
    atomicAdd(&lc[dst[i] >> BUCKET_SHIFT], 1);
  __syncthreads();
  for (int i = threadIdx.x; i < nbuck; i += 256)
    if (lc[i]) atomicAdd(&bcnt[i], lc[i]);
}

__global__ __launch_bounds__(1024) void bucket_scan(const int* __restrict__ bcnt,
                                                    int* __restrict__ bbase,
                                                    int* __restrict__ bcur, int nbuck) {
  __shared__ int s[1024];
  int t = threadIdx.x;
  int v = (t < nbuck) ? bcnt[t] : 0;
  s[t] = v;
  __syncthreads();
  for (int off = 1; off < 1024; off <<= 1) {
    int u = (t >= off) ? s[t - off] : 0;
    __syncthreads();
    s[t] += u;
    __syncthreads();
  }
  int excl = s[t] - v;
  if (t < nbuck) {
    bbase[t] = excl;
    bcur[t] = excl;
  } else if (t == nbuck) {
    bbase[t] = excl;
  }
}

__global__ __launch_bounds__(256) void bucket_scatter(const int* __restrict__ src,
                                                      const int* __restrict__ dst,
                                                      int* __restrict__ bcur,
                                                      int2* __restrict__ bucketed,
                                                      int e, int nbuck) {
  __shared__ int lcnt[MAXBUCK], loff[MAXBUCK], lcur[MAXBUCK], gbase[MAXBUCK];
  __shared__ int stmp[256];
  __shared__ int scarry;
  int t = threadIdx.x;
  int tile0 = blockIdx.x * TILE;
  int tn = min(TILE, e - tile0);
  __shared__ int2 lout[TILE];

  for (int i = t; i < nbuck; i += 256) lcnt[i] = 0;
  if (t == 0) scarry = 0;
  __syncthreads();
  for (int i = t; i < tn; i += 256)
    atomicAdd(&lcnt[dst[tile0 + i] >> BUCKET_SHIFT], 1);
  __syncthreads();
  for (int c0 = 0; c0 < nbuck; c0 += 256) {
    int idx = c0 + t;
    int v = (idx < nbuck) ? lcnt[idx] : 0;
    stmp[t] = v;
    __syncthreads();
    for (int off = 1; off < 256; off <<= 1) {
      int u = (t >= off) ? stmp[t - off] : 0;
      __syncthreads();
      stmp[t] += u;
      __syncthreads();
    }
    int excl = stmp[t] - v + scarry;
    if (idx < nbuck) { loff[idx] = excl; lcur[idx] = excl; }
    __syncthreads();
    if (t == 255) scarry += stmp[255];
    __syncthreads();
  }
  for (int i = t; i < tn; i += 256) {
    int d = dst[tile0 + i];
    int s = src[tile0 + i];
    int b = d >> BUCKET_SHIFT;
    int pos = atomicAdd(&lcur[b], 1);
    lout[pos] = make_int2(s, d);
  }
  __syncthreads();
  for (int i = t; i < nbuck; i += 256)
    if (lcnt[i] > 0) gbase[i] = atomicAdd(&bcur[i], lcnt[i]);
  __syncthreads();
  for (int j = t; j < tn; j += 256) {
    int2 v = lout[j];
    int b = v.y >> BUCKET_SHIFT;
    bucketed[gbase[b] + (j - loff[b])] = v;
  }
}

__global__ __launch_bounds__(256) void bucket_to_csr(const int2* __restrict__ bucketed,
                                                     const int* __restrict__ bbase,
                                                     int* __restrict__ rp,
                                                     float* __restrict__ dinv,
                                                     int* __restrict__ csr,
                                                     int n, int e, int nbuck) {
  __shared__ int lcnt[256], lrp[256];
  int b = blockIdx.x, t = threadIdx.x;
  int n0 = b << BUCKET_SHIFT;
  int base = bbase[b];
  int cnt_e = bbase[b + 1] - base;
  lcnt[t] = 0;
  __syncthreads();
  for (int i = t; i < cnt_e; i += 256)
    atomicAdd(&lcnt[bucketed[base + i].y & BUCKET_MASK], 1);
  __syncthreads();
  int v = lcnt[t];
  lrp[t] = v;
  __syncthreads();
  for (int off = 1; off < 256; off <<= 1) {
    int u = (t >= off) ? lrp[t - off] : 0;
    __syncthreads();
    lrp[t] += u;
    __syncthreads();
  }
  int excl = lrp[t] - v;
  int node = n0 + t;
  if (node < n) {
    rp[node] = base + excl;
    dinv[node] = rsqrtf((float)v + 1.0f);   // +1 self loop
  }
  if (b == nbuck - 1 && t == 0) rp[n] = e;
  lrp[t] = excl;
  lcnt[t] = 0;
  __syncthreads();
  for (int i = t; i < cnt_e; i += 256) {
    int2 ed = bucketed[base + i];
    int li = ed.y & BUCKET_MASK;
    int pos = atomicAdd(&lcnt[li], 1);
    csr[base + lrp[li] + pos] = ed.x;
  }
}

// ---------------- graph boundaries from sorted batch (no atomics) ----------------
__global__ void graph_bounds(const int* __restrict__ batch, int* __restrict__ gstart,
                             int n, int g) {
  int i = blockIdx.x * blockDim.x + threadIdx.x;
  if (i >= n) return;
  int b = batch[i];
  int bp = (i == 0) ? -1 : batch[i - 1];
  for (int k = bp + 1; k <= b; ++k) gstart[k] = i;
  if (i == n - 1)
    for (int k = b + 1; k <= g; ++k) gstart[k] = n;
}

// ---------------- layer 1: pre-scale x by dinv, aggregate, then linear ----------
__global__ void xs_scale(const float* __restrict__ x, const float* __restrict__ dinv,
                         float4* __restrict__ xs, int n) {
  int i = blockIdx.x * blockDim.x + threadIdx.x;
  if (i >= n) return;
  float d = dinv[i];
  xs[i] = make_float4(x[3 * (size_t)i] * d, x[3 * (size_t)i + 1] * d,
                      x[3 * (size_t)i + 2] * d, d);
}

__global__ void agg_f3(const float4* __restrict__ xs, const int* __restrict__ rp,
                       const int* __restrict__ csr, const float* __restrict__ dinv,
                       float* __restrict__ out, int n) {
  int i = blockIdx.x * blockDim.x + threadIdx.x;
  if (i >= n) return;
  float4 self = xs[i];
  float a0 = self.x, a1 = self.y, a2 = self.z;
  int e0 = rp[i], e1 = rp[i + 1];
  int e = e0;
  for (; e + 4 <= e1; e += 4) {
    int s0 = csr[e], s1 = csr[e + 1], s2 = csr[e + 2], s3 = csr[e + 3];
    float4 v0 = xs[s0], v1 = xs[s1], v2 = xs[s2], v3 = xs[s3];
    a0 += (v0.x + v1.x) + (v2.x + v3.x);
    a1 += (v0.y + v1.y) + (v2.y + v3.y);
    a2 += (v0.z + v1.z) + (v2.z + v3.z);
  }
  for (; e < e1; ++e) {
    float4 v = xs[csr[e]];
    a0 += v.x; a1 += v.y; a2 += v.z;
  }
  float d = dinv[i];
  out[4 * (size_t)i + 0] = a0 * d;
  out[4 * (size_t)i + 1] = a1 * d;
  out[4 * (size_t)i + 2] = a2 * d;
}

__global__ void lin_f3(const float* __restrict__ ag, const float* __restrict__ W1,
                       const float* __restrict__ b1, float* __restrict__ out, int n) {
  int idx = blockIdx.x * blockDim.x + threadIdx.x;
  if (idx >= n * 128) return;
  int node = idx >> 7, f = idx & 127;
  float a = b1[f]
          + ag[4 * (size_t)node + 0] * W1[f]
          + ag[4 * (size_t)node + 1] * W1[128 + f]
          + ag[4 * (size_t)node + 2] * W1[256 + f];
  out[idx] = a;
}

// ---------------- batch norm ----------------
__global__ void bn_stats(const float* __restrict__ x, float* __restrict__ stats, int n) {
  int t = threadIdx.x;
  int f = t & 127, half = t >> 7;
  float s = 0.f, q = 0.f;
  for (int r = blockIdx.x * 2 + half; r < n; r += gridDim.x * 2) {
    float v = x[(size_t)r * 128 + f];
    s += v;
    q += v * v;
  }
  __shared__ float ls[256], lq[256];
  ls[t] = s; lq[t] = q;
  __syncthreads();
  if (half == 0) {
    atomicAdd(&stats[f], s + ls[t + 128]);
    atomicAdd(&stats[128 + f], q + lq[t + 128]);
  }
}

// BN+ReLU, writes bf16 (feeds the MFMA GEMM)
__global__ void bn_apply_relu_bf16(const float* __restrict__ x,
                                   unsigned short* __restrict__ out,
                                   const float* __restrict__ stats,
                                   const float* __restrict__ gam, const float* __restrict__ bet,
                                   int n, float invn) {
  int idx = blockIdx.x * blockDim.x + threadIdx.x;
  if (idx >= n * 128) return;
  int f = idx & 127;
  float mu = stats[f] * invn;
  float var = stats[128 + f] * invn - mu * mu;
  float sc = rsqrtf(var + 1e-5f) * gam[f];
  float v = (x[idx] - mu) * sc + bet[f];
  out[idx] = f2bf(fmaxf(v, 0.0f));
}

// ---------------- W split-transpose: W[k][f] fp32 -> Wt[f][k] hi/lo bf16 ---------
__global__ void wsplit(const float* __restrict__ W, unsigned short* __restrict__ Wt2) {
  int i = blockIdx.x * 256 + threadIdx.x;   // 16384 elements
  if (i >= 128 * 128) return;
  int k = i >> 7, f = i & 127;
  float w = W[i];
  unsigned short hi = f2bf(w);
  float hif = __uint_as_float((unsigned)hi << 16);
  unsigned short lo = f2bf(w - hif);
  Wt2[f * 128 + k] = hi;
  Wt2[128 * 128 + f * 128 + k] = lo;
}

// ------ MFMA GEMM: [n,128] bf16 @ (Wt hi+lo) -> [n,128] bf16, row-scaled by dinv --
__global__ __launch_bounds__(256) void gemm_mfma(const unsigned short* __restrict__ Abf,
                                                 const unsigned short* __restrict__ Wt2,
                                                 const float* __restrict__ dinv,
                                                 unsigned short* __restrict__ C, int n) {
  const int t = threadIdx.x;
  const int wave = t >> 6, lane = t & 63;
  const int l15 = lane & 15, lg = lane >> 4;        // lg = k-group (A/B), row-group (C/D)
  const int row0 = blockIdx.x * 64 + wave * 16;     // wave's 16-row tile
  const int arow = row0 + l15;
  const unsigned short* Wlo = Wt2 + 128 * 128;
  f32x4 acc0 = {0.f, 0.f, 0.f, 0.f}, acc1 = acc0, acc2 = acc0, acc3 = acc0;
  f32x4 acc4 = acc0, acc5 = acc0, acc6 = acc0, acc7 = acc0;
#pragma unroll
  for (int ks = 0; ks < 4; ++ks) {
    int kb = ks * 32 + lg * 8;
    bf16x8 af = {};
    if (arow < n) af = *(const bf16x8*)&Abf[(size_t)arow * 128 + kb];
#define GSTEP(NT, ACC)                                                              \
    {                                                                               \
      bf16x8 bh = *(const bf16x8*)&Wt2[(size_t)(NT * 16 + l15) * 128 + kb];         \
      bf16x8 bl = *(const bf16x8*)&Wlo[(size_t)(NT * 16 + l15) * 128 + kb];         \
      ACC = __builtin_amdgcn_mfma_f32_16x16x32_bf16(af, bh, ACC, 0, 0, 0);          \
      ACC = __builtin_amdgcn_mfma_f32_16x16x32_bf16(af, bl, ACC, 0, 0, 0);          \
    }
    GSTEP(0, acc0) GSTEP(1, acc1) GSTEP(2, acc2) GSTEP(3, acc3)
    GSTEP(4, acc4) GSTEP(5, acc5) GSTEP(6, acc6) GSTEP(7, acc7)
#undef GSTEP
  }
  // C/D layout: col = l15 (+16*nt), row = row0 + lg*4 + r
#pragma unroll
  for (int r = 0; r < 4; ++r) {
    int orow = row0 + lg * 4 + r;
    if (orow < n) {
      float sc = dinv[orow];
      unsigned short* cp = &C[(size_t)orow * 128 + l15];
      cp[0]   = f2bf(acc0[r] * sc);
      cp[16]  = f2bf(acc1[r] * sc);
      cp[32]  = f2bf(acc2[r] * sc);
      cp[48]  = f2bf(acc3[r] * sc);
      cp[64]  = f2bf(acc4[r] * sc);
      cp[80]  = f2bf(acc5[r] * sc);
      cp[96]  = f2bf(acc6[r] * sc);
      cp[112] = f2bf(acc7[r] * sc);
    }
  }
}

// ------- aggregation of pre-scaled bf16 rows: 16 lanes/node, 8 bf16/lane --------
__global__ __launch_bounds__(256) void agg128_bf16(const unsigned short* __restrict__ h,
                                                   const int* __restrict__ rp,
                                                   const int* __restrict__ csr,
                                                   const float* __restrict__ dinv,
                                                   const float* __restrict__ bias,
                                                   float* __restrict__ out, int n) {
  int node = blockIdx.x * 16 + (threadIdx.x >> 4);
  int lane = threadIdx.x & 15;
  if (node >= n) return;
  const uint4* hp = (const uint4*)h;             // row = 16 uint4 (256 B)
  float acc[8] = {0.f};
  acc8(acc, hp[(size_t)node * 16 + lane]);       // self term (pre-scaled)
  int e0 = rp[node], e1 = rp[node + 1];
  int e = e0;
  for (; e + 4 <= e1; e += 4) {
    int s0 = csr[e], s1 = csr[e + 1], s2 = csr[e + 2], s3 = csr[e + 3];
    uint4 v0 = hp[(size_t)s0 * 16 + lane];
    uint4 v1 = hp[(size_t)s1 * 16 + lane];
    uint4 v2 = hp[(size_t)s2 * 16 + lane];
    uint4 v3 = hp[(size_t)s3 * 16 + lane];
    acc8(acc, v0); acc8(acc, v1); acc8(acc, v2); acc8(acc, v3);
  }
  for (; e < e1; ++e) acc8(acc, hp[(size_t)csr[e] * 16 + lane]);
  float dd = dinv[node];
  float4 bb0 = *(const float4*)&bias[lane * 8];
  float4 bb1 = *(const float4*)&bias[lane * 8 + 4];
  float4 o0 = make_float4(acc[0] * dd + bb0.x, acc[1] * dd + bb0.y,
                          acc[2] * dd + bb0.z, acc[3] * dd + bb0.w);
  float4 o1 = make_float4(acc[4] * dd + bb1.x, acc[5] * dd + bb1.y,
                          acc[6] * dd + bb1.z, acc[7] * dd + bb1.w);
  *(float4*)&out[(size_t)node * 128 + lane * 8] = o0;
  *(float4*)&out[(size_t)node * 128 + lane * 8 + 4] = o1;
}

// ---------------- pooling ----------------
__global__ void pool_partial(const float* __restrict__ z, const int* __restrict__ gstart,
                             float* __restrict__ pooled) {
  int g = blockIdx.x >> 3, p = blockIdx.x & 7;
  int t = threadIdx.x;
  int f = t & 127, half = t >> 7;
  int beg = gstart[g], end = gstart[g + 1];
  float s = 0.f;
  for (int idx = beg + p * 2 + half; idx < end; idx += 16)
    s += z[(size_t)idx * 128 + f];
  __shared__ float ls[256];
  ls[t] = s;
  __syncthreads();
  if (half == 0) atomicAdd(&pooled[g * 128 + f], s + ls[t + 128]);
}

// ---------------- MLP head + L2 normalize ----------------
__global__ void mlp_kernel(const float* __restrict__ pooled, const int* __restrict__ gstart,
                           const float* __restrict__ Wp1, const float* __restrict__ bp1,
                           const float* __restrict__ Wp2, const float* __restrict__ bp2,
                           float* __restrict__ out) {
  int g = blockIdx.x, t = threadIdx.x;
  __shared__ float pv[128], hid[128], ov[512], red[256];
  if (t < 128) {
    float cntf = (float)(gstart[g + 1] - gstart[g]);
    pv[t] = pooled[g * 128 + t] / fmaxf(cntf, 1.0f);
  }
  __syncthreads();
  if (t < 128) {
    float a = bp1[t];
    for (int k = 0; k < 128; ++k) a += pv[k] * Wp1[k * 128 + t];
    hid[t] = fmaxf(a, 0.0f);
  }
  __syncthreads();
  for (int o = t; o < 512; o += 256) {
    float a = bp2[o];
    for (int k = 0; k < 128; ++k) a += hid[k] * Wp2[k * 512 + o];
    ov[o] = a;
  }
  __syncthreads();
  red[t] = ov[t] * ov[t] + ov[t + 256] * ov[t + 256];
  __syncthreads();
  for (int sdt = 128; sdt > 0; sdt >>= 1) {
    if (t < sdt) red[t] += red[t + sdt];
    __syncthreads();
  }
  float inv = 1.0f / fmaxf(sqrtf(red[0]), 1e-12f);
  for (int o = t; o < 512; o += 256) out[(size_t)g * 512 + o] = ov[o] * inv;
}

// ---------------- host orchestration ----------------
extern "C" void kernel_launch(void* const* d_in, const int* in_sizes, int n_in,
                              void* d_out, int out_size, void* d_ws, size_t ws_size,
                              hipStream_t stream) {
  const int N = in_sizes[0] / 3;
  const int E = in_sizes[1] / 2;
  const int G = out_size / (2 * 512);
  const int NBUCK = (N + BUCKET_MASK) >> BUCKET_SHIFT;

  char* w = (char*)d_ws;
  auto alloc = [&](size_t bytes) -> void* {
    void* p = (void*)w;
    w += (bytes + 255) & ~(size_t)255;
    return p;
  };
  float*          A        = (float*)alloc((size_t)N * 128 * 4);
  unsigned short* Abf      = (unsigned short*)alloc((size_t)N * 128 * 2);
  unsigned short* Bh       = (unsigned short*)alloc((size_t)N * 128 * 2);
  float*          dinv     = (float*)alloc((size_t)N * 4);
  float4*         xs       = (float4*)alloc((size_t)N * 16);
  float*          ag0      = (float*)alloc((size_t)N * 16);
  int*            rp       = (int*)alloc((size_t)(N + 1) * 4);
  int*            csr      = (int*)alloc((size_t)E * 4);
  int2*           bucketed = (int2*)alloc((size_t)E * 8);
  int*            bcnt     = (int*)alloc((size_t)NBUCK * 4);
  int*            bbase    = (int*)alloc((size_t)(NBUCK + 1) * 4);
  int*            bcur     = (int*)alloc((size_t)NBUCK * 4);
  float*          stats    = (float*)alloc(256 * 4);
  int*            gstart   = (int*)alloc((size_t)(G + 1) * 4);
  float*          pooled   = (float*)alloc((size_t)G * 128 * 4);
  unsigned short* Wt2      = (unsigned short*)alloc(2 * 128 * 128 * 2);  // W2 hi/lo
  unsigned short* Wt3      = (unsigned short*)alloc(2 * 128 * 128 * 2);  // W3 hi/lo

  const float* W1  = (const float*)d_in[6];
  const float* b1  = (const float*)d_in[7];
  const float* W2  = (const float*)d_in[8];
  const float* b2  = (const float*)d_in[9];
  const float* W3  = (const float*)d_in[10];
  const float* b3  = (const float*)d_in[11];
  const float* g1  = (const float*)d_in[12];
  const float* be1 = (const float*)d_in[13];
  const float* g2  = (const float*)d_in[14];
  const float* be2 = (const float*)d_in[15];
  const float* Wp1 = (const float*)d_in[16];
  const float* bp1 = (const float*)d_in[17];
  const float* Wp2 = (const float*)d_in[18];
  const float* bp2 = (const float*)d_in[19];

  const int TB = 256;

  // split-transpose weights once (shared by both branches)
  wsplit<<<64, TB, 0, stream>>>(W2, Wt2);
  wsplit<<<64, TB, 0, stream>>>(W3, Wt3);

  for (int br = 0; br < 2; ++br) {
    const float* x   = (const float*)d_in[br * 3 + 0];
    const int* ei    = (const int*)d_in[br * 3 + 1];
    const int* src   = ei;
    const int* dst   = ei + E;
    const int* batch = (const int*)d_in[br * 3 + 2];
    float* outp = (float*)d_out + (size_t)br * G * 512;

    // bucketed CSR build (by dst) + degrees + rp
    zero_u32<<<(NBUCK + TB - 1) / TB, TB, 0, stream>>>((unsigned*)bcnt, NBUCK);
    bucket_count<<<256, TB, 0, stream>>>(dst, bcnt, E, NBUCK);
    bucket_scan<<<1, 1024, 0, stream>>>(bcnt, bbase, bcur, NBUCK);
    bucket_scatter<<<(E + TILE - 1) / TILE, TB, 0, stream>>>(src, dst, bcur, bucketed, E, NBUCK);
    bucket_to_csr<<<NBUCK, TB, 0, stream>>>(bucketed, bbase, rp, dinv, csr, N, E, NBUCK);

    // graph boundaries from sorted batch (no atomics)
    graph_bounds<<<(N + TB - 1) / TB, TB, 0, stream>>>(batch, gstart, N, G);

    // layer 1: pre-scale x, aggregate (pre-scaled), linear -> A
    xs_scale<<<(N + TB - 1) / TB, TB, 0, stream>>>(x, dinv, xs, N);
    agg_f3<<<(N + TB - 1) / TB, TB, 0, stream>>>(xs, rp, csr, dinv, ag0, N);
    lin_f3<<<(N * 128 + TB - 1) / TB, TB, 0, stream>>>(ag0, W1, b1, A, N);
    zero_u32<<<1, TB, 0, stream>>>((unsigned*)stats, 256);
    bn_stats<<<1024, TB, 0, stream>>>(A, stats, N);
    bn_apply_relu_bf16<<<(N * 128 + TB - 1) / TB, TB, 0, stream>>>(A, Abf, stats, g1, be1, N, 1.0f / (float)N);

    // layer 2: MFMA gemm (dinv-scaled bf16 out) -> sum-agg -> final dinv scale
    gemm_mfma<<<(N + 63) / 64, TB, 0, stream>>>(Abf, Wt2, dinv, Bh, N);
    agg128_bf16<<<(N + 15) / 16, TB, 0, stream>>>(Bh, rp, csr, dinv, b2, A, N);
    zero_u32<<<1, TB, 0, stream>>>((unsigned*)stats, 256);
    bn_stats<<<1024, TB, 0, stream>>>(A, stats, N);
    bn_apply_relu_bf16<<<(N * 128 + TB - 1) / TB, TB, 0, stream>>>(A, Abf, stats, g2, be2, N, 1.0f / (float)N);

    // layer 3
    gemm_mfma<<<(N + 63) / 64, TB, 0, stream>>>(Abf, Wt3, dinv, Bh, N);
    agg128_bf16<<<(N + 15) / 16, TB, 0, stream>>>(Bh, rp, csr, dinv, b3, A, N);

    // pool
    zero_u32<<<(G * 128 + TB - 1) / TB, TB, 0, stream>>>((unsigned*)pooled, G * 128);
    pool_partial<<<G * 8, TB, 0, stream>>>(A, gstart, pooled);

    // MLP head + normalize
    mlp_kernel<<<G, TB, 0, stream>>>(pooled, gstart, Wp1, bp1, Wp2, bp2, outp);
  }
}

// Round 7
// 1032.300 us; speedup vs baseline: 1.3166x; 1.3166x over previous
//
#include <hip/hip_runtime.h>
#include <math.h>

#define BUCKET_SHIFT 8            // 256 nodes per bucket
#define BUCKET_MASK 255
#define MAXBUCK 640               // supports N <= 163840
#define TILE 8192

typedef __attribute__((ext_vector_type(8))) short bf16x8;
typedef __attribute__((ext_vector_type(4))) float f32x4;

__device__ inline float bf_lo(unsigned u) { return __uint_as_float(u << 16); }
__device__ inline float bf_hi(unsigned u) { return __uint_as_float(u & 0xffff0000u); }
__device__ inline unsigned short f2bf(float f) {   // round-to-nearest-even
  unsigned u = __float_as_uint(f);
  return (unsigned short)((u + 0x7fffu + ((u >> 16) & 1u)) >> 16);
}
__device__ inline void acc8(float* a, uint4 v) {
  a[0] += bf_lo(v.x); a[1] += bf_hi(v.x);
  a[2] += bf_lo(v.y); a[3] += bf_hi(v.y);
  a[4] += bf_lo(v.z); a[5] += bf_hi(v.z);
  a[6] += bf_lo(v.w); a[7] += bf_hi(v.w);
}

// ---------------- utility ----------------
__global__ void zero_u32(unsigned int* __restrict__ p, int n) {
  int i = blockIdx.x * blockDim.x + threadIdx.x;
  if (i < n) p[i] = 0u;
}

// ---------------- bucketed CSR build ----------------
__global__ __launch_bounds__(256) void bucket_count(const int* __restrict__ dst,
                                                    int* __restrict__ bcnt, int e, int nbuck) {
  __shared__ int lc[MAXBUCK];
  for (int i = threadIdx.x; i < nbuck; i += 256) lc[i] = 0;
  __syncthreads();
  for (int i = blockIdx.x * blockDim.x + threadIdx.x; i < e; i += gridDim.x * blockDim.x)
    atomicAdd(&lc[dst[i] >> BUCKET_SHIFT], 1);
  __syncthreads();
  for (int i = threadIdx.x; i < nbuck; i += 256)
    if (lc[i]) atomicAdd(&bcnt[i], lc[i]);
}

__global__ __launch_bounds__(1024) void bucket_scan(const int* __restrict__ bcnt,
                                                    int* __restrict__ bbase,
                                                    int* __restrict__ bcur, int nbuck) {
  __shared__ int s[1024];
  int t = threadIdx.x;
  int v = (t < nbuck) ? bcnt[t] : 0;
  s[t] = v;
  __syncthreads();
  for (int off = 1; off < 1024; off <<= 1) {
    int u = (t >= off) ? s[t - off] : 0;
    __syncthreads();
    s[t] += u;
    __syncthreads();
  }
  int excl = s[t] - v;
  if (t < nbuck) {
    bbase[t] = excl;
    bcur[t] = excl;
  } else if (t == nbuck) {
    bbase[t] = excl;
  }
}

// packs edge as (src<<8)|(dst&255); bucket id kept in a side LDS array
__global__ __launch_bounds__(256) void bucket_scatter2(const int* __restrict__ src,
                                                       const int* __restrict__ dst,
                                                       int* __restrict__ bcur,
                                                       int* __restrict__ bucketed,
                                                       int e, int nbuck) {
  __shared__ int lcnt[MAXBUCK], loff[MAXBUCK], lcur[MAXBUCK], gbase[MAXBUCK];
  __shared__ int stmp[256];
  __shared__ int scarry;
  int t = threadIdx.x;
  int tile0 = blockIdx.x * TILE;
  int tn = min(TILE, e - tile0);
  __shared__ int lout[TILE];
  __shared__ unsigned short lbk[TILE];

  for (int i = t; i < nbuck; i += 256) lcnt[i] = 0;
  if (t == 0) scarry = 0;
  __syncthreads();
  for (int i = t; i < tn; i += 256)
    atomicAdd(&lcnt[dst[tile0 + i] >> BUCKET_SHIFT], 1);
  __syncthreads();
  for (int c0 = 0; c0 < nbuck; c0 += 256) {
    int idx = c0 + t;
    int v = (idx < nbuck) ? lcnt[idx] : 0;
    stmp[t] = v;
    __syncthreads();
    for (int off = 1; off < 256; off <<= 1) {
      int u = (t >= off) ? stmp[t - off] : 0;
      __syncthreads();
      stmp[t] += u;
      __syncthreads();
    }
    int excl = stmp[t] - v + scarry;
    if (idx < nbuck) { loff[idx] = excl; lcur[idx] = excl; }
    __syncthreads();
    if (t == 255) scarry += stmp[255];
    __syncthreads();
  }
  for (int i = t; i < tn; i += 256) {
    int d = dst[tile0 + i];
    int s = src[tile0 + i];
    int b = d >> BUCKET_SHIFT;
    int pos = atomicAdd(&lcur[b], 1);
    lout[pos] = (s << 8) | (d & BUCKET_MASK);
    lbk[pos] = (unsigned short)b;
  }
  __syncthreads();
  for (int i = t; i < nbuck; i += 256)
    if (lcnt[i] > 0) gbase[i] = atomicAdd(&bcur[i], lcnt[i]);
  __syncthreads();
  for (int j = t; j < tn; j += 256) {
    int b = lbk[j];
    bucketed[gbase[b] + (j - loff[b])] = lout[j];
  }
}

__global__ __launch_bounds__(256) void bucket_to_csr(const int* __restrict__ bucketed,
                                                     const int* __restrict__ bbase,
                                                     int* __restrict__ rp,
                                                     float* __restrict__ dinv,
                                                     int* __restrict__ csr,
                                                     int n, int e, int nbuck) {
  __shared__ int lcnt[256], lrp[256];
  int b = blockIdx.x, t = threadIdx.x;
  int n0 = b << BUCKET_SHIFT;
  int base = bbase[b];
  int cnt_e = bbase[b + 1] - base;
  lcnt[t] = 0;
  __syncthreads();
  for (int i = t; i < cnt_e; i += 256)
    atomicAdd(&lcnt[bucketed[base + i] & BUCKET_MASK], 1);
  __syncthreads();
  int v = lcnt[t];
  lrp[t] = v;
  __syncthreads();
  for (int off = 1; off < 256; off <<= 1) {
    int u = (t >= off) ? lrp[t - off] : 0;
    __syncthreads();
    lrp[t] += u;
    __syncthreads();
  }
  int excl = lrp[t] - v;
  int node = n0 + t;
  if (node < n) {
    rp[node] = base + excl;
    dinv[node] = rsqrtf((float)v + 1.0f);   // +1 self loop
  }
  if (b == nbuck - 1 && t == 0) rp[n] = e;
  lrp[t] = excl;
  lcnt[t] = 0;
  __syncthreads();
  for (int i = t; i < cnt_e; i += 256) {
    int ed = bucketed[base + i];
    int li = ed & BUCKET_MASK;
    int pos = atomicAdd(&lcnt[li], 1);
    csr[base + lrp[li] + pos] = (int)(((unsigned)ed) >> 8);
  }
}

// ---------------- graph boundaries from sorted batch (no atomics) ----------------
__global__ void graph_bounds(const int* __restrict__ batch, int* __restrict__ gstart,
                             int n, int g) {
  int i = blockIdx.x * blockDim.x + threadIdx.x;
  if (i >= n) return;
  int b = batch[i];
  int bp = (i == 0) ? -1 : batch[i - 1];
  for (int k = bp + 1; k <= b; ++k) gstart[k] = i;
  if (i == n - 1)
    for (int k = b + 1; k <= g; ++k) gstart[k] = n;
}

// ---------------- layer 1: pre-scale, aggregate + block moments ----------------
__global__ void xs_scale(const float* __restrict__ x, const float* __restrict__ dinv,
                         float4* __restrict__ xs, int n) {
  int i = blockIdx.x * blockDim.x + threadIdx.x;
  if (i >= n) return;
  float d = dinv[i];
  xs[i] = make_float4(x[3 * (size_t)i] * d, x[3 * (size_t)i + 1] * d,
                      x[3 * (size_t)i + 2] * d, d);
}

__global__ __launch_bounds__(256) void agg_f3(const float4* __restrict__ xs,
                                              const int* __restrict__ rp,
                                              const int* __restrict__ csr,
                                              const float* __restrict__ dinv,
                                              float4* __restrict__ out,
                                              float* __restrict__ mpart, int n) {
  int i = blockIdx.x * blockDim.x + threadIdx.x;
  int t = threadIdx.x;
  float a0 = 0.f, a1 = 0.f, a2 = 0.f;
  if (i < n) {
    float4 self = xs[i];
    a0 = self.x; a1 = self.y; a2 = self.z;
    int e0 = rp[i], e1 = rp[i + 1];
    int e = e0;
    for (; e + 4 <= e1; e += 4) {
      int s0 = csr[e], s1 = csr[e + 1], s2 = csr[e + 2], s3 = csr[e + 3];
      float4 v0 = xs[s0], v1 = xs[s1], v2 = xs[s2], v3 = xs[s3];
      a0 += (v0.x + v1.x) + (v2.x + v3.x);
      a1 += (v0.y + v1.y) + (v2.y + v3.y);
      a2 += (v0.z + v1.z) + (v2.z + v3.z);
    }
    for (; e < e1; ++e) {
      float4 v = xs[csr[e]];
      a0 += v.x; a1 += v.y; a2 += v.z;
    }
    float d = dinv[i];
    a0 *= d; a1 *= d; a2 *= d;
    out[i] = make_float4(a0, a1, a2, 0.f);
  }
  float loc[9] = {a0, a1, a2, a0 * a0, a0 * a1, a0 * a2, a1 * a1, a1 * a2, a2 * a2};
  __shared__ float red[256];
  for (int q = 0; q < 9; ++q) {
    red[t] = loc[q];
    __syncthreads();
    for (int s = 128; s > 0; s >>= 1) {
      if (t < s) red[t] += red[t + s];
      __syncthreads();
    }
    if (t == 0) mpart[blockIdx.x * 9 + q] = red[0];
    __syncthreads();
  }
}

__global__ void bnprep1(const float* __restrict__ mpart, int nblk,
                        const float* __restrict__ W1, const float* __restrict__ b1,
                        const float* __restrict__ g1, const float* __restrict__ be1,
                        float invn, float4* __restrict__ W1r, float2* __restrict__ prm) {
  __shared__ float red[256];
  __shared__ float sm[9];
  int t = threadIdx.x;
  float loc[9] = {0.f, 0.f, 0.f, 0.f, 0.f, 0.f, 0.f, 0.f, 0.f};
  for (int i = t; i < nblk; i += 256)
#pragma unroll
    for (int q = 0; q < 9; ++q) loc[q] += mpart[i * 9 + q];
  for (int q = 0; q < 9; ++q) {
    red[t] = loc[q];
    __syncthreads();
    for (int s = 128; s > 0; s >>= 1) {
      if (t < s) red[t] += red[t + s];
      __syncthreads();
    }
    if (t == 0) sm[q] = red[0] * invn;
    __syncthreads();
  }
  if (t < 128) {
    float w0 = W1[t], w1 = W1[128 + t], w2 = W1[256 + t], b = b1[t];
    float mu0 = sm[0] * w0 + sm[1] * w1 + sm[2] * w2;
    float q2 = w0 * w0 * sm[3] + w1 * w1 * sm[6] + w2 * w2 * sm[8]
             + 2.f * (w0 * w1 * sm[4] + w0 * w2 * sm[5] + w1 * w2 * sm[7]);
    float var = q2 - mu0 * mu0;
    float sc = rsqrtf(fmaxf(var, 0.f) + 1e-5f) * g1[t];
    float mu = mu0 + b;
    W1r[t] = make_float4(w0, w1, w2, b);
    prm[t] = make_float2(sc, be1[t] - mu * sc);
  }
}

__global__ void lin1_fused(const float4* __restrict__ ag, const float4* __restrict__ W1r,
                           const float2* __restrict__ prm, unsigned short* __restrict__ out,
                           int n128) {
  int idx = blockIdx.x * blockDim.x + threadIdx.x;
  if (idx >= n128) return;
  int node = idx >> 7, f = idx & 127;
  float4 a = ag[node];
  float4 w = W1r[f];
  float2 p = prm[f];
  float v = a.x * w.x + a.y * w.y + a.z * w.z + w.w;
  v = v * p.x + p.y;
  out[idx] = f2bf(fmaxf(v, 0.f));
}

// ---------------- batch norm (layers 2,3) ----------------
__global__ void bn_stats(const float* __restrict__ x, float* __restrict__ stats, int n) {
  int t = threadIdx.x;
  int f = t & 127, half = t >> 7;
  float s = 0.f, q = 0.f;
  for (int r = blockIdx.x * 2 + half; r < n; r += gridDim.x * 2) {
    float v = x[(size_t)r * 128 + f];
    s += v;
    q += v * v;
  }
  __shared__ float ls[256], lq[256];
  ls[t] = s; lq[t] = q;
  __syncthreads();
  if (half == 0) {
    atomicAdd(&stats[f], s + ls[t + 128]);
    atomicAdd(&stats[128 + f], q + lq[t + 128]);
  }
}

__global__ void bn_apply_relu_bf16(const float* __restrict__ x,
                                   unsigned short* __restrict__ out,
                                   const float* __restrict__ stats,
                                   const float* __restrict__ gam, const float* __restrict__ bet,
                                   int n, float invn) {
  int idx = blockIdx.x * blockDim.x + threadIdx.x;
  if (idx >= n * 128) return;
  int f = idx & 127;
  float mu = stats[f] * invn;
  float var = stats[128 + f] * invn - mu * mu;
  float sc = rsqrtf(var + 1e-5f) * gam[f];
  float v = (x[idx] - mu) * sc + bet[f];
  out[idx] = f2bf(fmaxf(v, 0.0f));
}

// ------- W split to MFMA-fragment-major layout: hi block then lo block ----------
__global__ void wsplit(const float* __restrict__ W, unsigned short* __restrict__ Wf) {
  int i = blockIdx.x * 256 + threadIdx.x;   // 16384 = 128x128
  if (i >= 128 * 128) return;
  int k = i >> 7, f = i & 127;
  float w = W[i];                            // W[k][f]
  unsigned short hi = f2bf(w);
  float hif = __uint_as_float((unsigned)hi << 16);
  unsigned short lo = f2bf(w - hif);
  int NT = f >> 4, l15 = f & 15, ks = k >> 5, lg = (k >> 3) & 3, j = k & 7;
  int lane = lg * 16 + l15;
  size_t base = ((size_t)(NT * 4 + ks) * 64 + lane) * 8 + j;
  Wf[base] = hi;
  Wf[16384 + base] = lo;
}

// ------ MFMA GEMM (swapped operands): D[feat, node], 32 rows/wave ---------------
__global__ __launch_bounds__(256) void gemm_mfma(const unsigned short* __restrict__ Abf,
                                                 const unsigned short* __restrict__ Wf,
                                                 const float* __restrict__ dinv,
                                                 unsigned short* __restrict__ C, int n) {
  const int t = threadIdx.x;
  const int wave = t >> 6, lane = t & 63;
  const int l15 = lane & 15, lg = lane >> 4;
  const int row0 = blockIdx.x * 128 + wave * 32;
  const int n0 = row0 + l15, n1 = row0 + 16 + l15;
  const bf16x8* wfr = (const bf16x8*)Wf;       // hi frags [0..2047], lo at +2048
  f32x4 acc[8][2] = {};
#pragma unroll
  for (int ks = 0; ks < 4; ++ks) {
    bf16x8 nf0 = {}, nf1 = {};
    if (n0 < n) nf0 = *(const bf16x8*)&Abf[(size_t)n0 * 128 + ks * 32 + lg * 8];
    if (n1 < n) nf1 = *(const bf16x8*)&Abf[(size_t)n1 * 128 + ks * 32 + lg * 8];
#pragma unroll
    for (int NT = 0; NT < 8; ++NT) {
      bf16x8 wh = wfr[(NT * 4 + ks) * 64 + lane];
      bf16x8 wl = wfr[2048 + (NT * 4 + ks) * 64 + lane];
      acc[NT][0] = __builtin_amdgcn_mfma_f32_16x16x32_bf16(wh, nf0, acc[NT][0], 0, 0, 0);
      acc[NT][0] = __builtin_amdgcn_mfma_f32_16x16x32_bf16(wl, nf0, acc[NT][0], 0, 0, 0);
      acc[NT][1] = __builtin_amdgcn_mfma_f32_16x16x32_bf16(wh, nf1, acc[NT][1], 0, 0, 0);
      acc[NT][1] = __builtin_amdgcn_mfma_f32_16x16x32_bf16(wl, nf1, acc[NT][1], 0, 0, 0);
    }
  }
  float sc0 = (n0 < n) ? dinv[n0] : 0.f;
  float sc1 = (n1 < n) ? dinv[n1] : 0.f;
#pragma unroll
  for (int ng = 0; ng < 2; ++ng) {
    int node = (ng == 0) ? n0 : n1;
    float sc = (ng == 0) ? sc0 : sc1;
    if (node < n) {
#pragma unroll
      for (int NT = 0; NT < 8; ++NT) {
        ushort4 o;
        o.x = f2bf(acc[NT][ng][0] * sc);
        o.y = f2bf(acc[NT][ng][1] * sc);
        o.z = f2bf(acc[NT][ng][2] * sc);
        o.w = f2bf(acc[NT][ng][3] * sc);
        *(ushort4*)&C[(size_t)node * 128 + NT * 16 + lg * 4] = o;
      }
    }
  }
}

// ------- aggregation of pre-scaled bf16 rows: 16 lanes/node, 8-deep pipeline ----
__global__ __launch_bounds__(256) void agg128_bf16(const unsigned short* __restrict__ h,
                                                   const int* __restrict__ rp,
                                                   const int* __restrict__ csr,
                                                   const float* __restrict__ dinv,
                                                   const float* __restrict__ bias,
                                                   float* __restrict__ out, int n) {
  int node = blockIdx.x * 16 + (threadIdx.x >> 4);
  int lane = threadIdx.x & 15;
  if (node >= n) return;
  const uint4* hp = (const uint4*)h;
  float acc[8] = {0.f};
  acc8(acc, hp[(size_t)node * 16 + lane]);
  int e0 = rp[node], e1 = rp[node + 1];
  int e = e0;
  for (; e + 8 <= e1; e += 8) {
    int s0 = csr[e],     s1 = csr[e + 1], s2 = csr[e + 2], s3 = csr[e + 3];
    int s4 = csr[e + 4], s5 = csr[e + 5], s6 = csr[e + 6], s7 = csr[e + 7];
    uint4 v0 = hp[(size_t)s0 * 16 + lane];
    uint4 v1 = hp[(size_t)s1 * 16 + lane];
    uint4 v2 = hp[(size_t)s2 * 16 + lane];
    uint4 v3 = hp[(size_t)s3 * 16 + lane];
    uint4 v4 = hp[(size_t)s4 * 16 + lane];
    uint4 v5 = hp[(size_t)s5 * 16 + lane];
    uint4 v6 = hp[(size_t)s6 * 16 + lane];
    uint4 v7 = hp[(size_t)s7 * 16 + lane];
    acc8(acc, v0); acc8(acc, v1); acc8(acc, v2); acc8(acc, v3);
    acc8(acc, v4); acc8(acc, v5); acc8(acc, v6); acc8(acc, v7);
  }
  for (; e + 4 <= e1; e += 4) {
    int s0 = csr[e], s1 = csr[e + 1], s2 = csr[e + 2], s3 = csr[e + 3];
    uint4 v0 = hp[(size_t)s0 * 16 + lane];
    uint4 v1 = hp[(size_t)s1 * 16 + lane];
    uint4 v2 = hp[(size_t)s2 * 16 + lane];
    uint4 v3 = hp[(size_t)s3 * 16 + lane];
    acc8(acc, v0); acc8(acc, v1); acc8(acc, v2); acc8(acc, v3);
  }
  for (; e < e1; ++e) acc8(acc, hp[(size_t)csr[e] * 16 + lane]);
  float dd = dinv[node];
  float4 bb0 = *(const float4*)&bias[lane * 8];
  float4 bb1 = *(const float4*)&bias[lane * 8 + 4];
  float4 o0 = make_float4(acc[0] * dd + bb0.x, acc[1] * dd + bb0.y,
                          acc[2] * dd + bb0.z, acc[3] * dd + bb0.w);
  float4 o1 = make_float4(acc[4] * dd + bb1.x, acc[5] * dd + bb1.y,
                          acc[6] * dd + bb1.z, acc[7] * dd + bb1.w);
  *(float4*)&out[(size_t)node * 128 + lane * 8] = o0;
  *(float4*)&out[(size_t)node * 128 + lane * 8 + 4] = o1;
}

// ---------------- pooling ----------------
__global__ void pool_partial(const float* __restrict__ z, const int* __restrict__ gstart,
                             float* __restrict__ pooled) {
  int g = blockIdx.x >> 3, p = blockIdx.x & 7;
  int t = threadIdx.x;
  int f = t & 127, half = t >> 7;
  int beg = gstart[g], end = gstart[g + 1];
  float s = 0.f;
  for (int idx = beg + p * 2 + half; idx < end; idx += 16)
    s += z[(size_t)idx * 128 + f];
  __shared__ float ls[256];
  ls[t] = s;
  __syncthreads();
  if (half == 0) atomicAdd(&pooled[g * 128 + f], s + ls[t + 128]);
}

// ---------------- MLP head + L2 normalize ----------------
__global__ void mlp_kernel(const float* __restrict__ pooled, const int* __restrict__ gstart,
                           const float* __restrict__ Wp1, const float* __restrict__ bp1,
                           const float* __restrict__ Wp2, const float* __restrict__ bp2,
                           float* __restrict__ out) {
  int g = blockIdx.x, t = threadIdx.x;
  __shared__ float pv[128], hid[128], ov[512], red[256];
  if (t < 128) {
    float cntf = (float)(gstart[g + 1] - gstart[g]);
    pv[t] = pooled[g * 128 + t] / fmaxf(cntf, 1.0f);
  }
  __syncthreads();
  if (t < 128) {
    float a = bp1[t];
    for (int k = 0; k < 128; ++k) a += pv[k] * Wp1[k * 128 + t];
    hid[t] = fmaxf(a, 0.0f);
  }
  __syncthreads();
  for (int o = t; o < 512; o += 256) {
    float a = bp2[o];
    for (int k = 0; k < 128; ++k) a += hid[k] * Wp2[k * 512 + o];
    ov[o] = a;
  }
  __syncthreads();
  red[t] = ov[t] * ov[t] + ov[t + 256] * ov[t + 256];
  __syncthreads();
  for (int sdt = 128; sdt > 0; sdt >>= 1) {
    if (t < sdt) red[t] += red[t + sdt];
    __syncthreads();
  }
  float inv = 1.0f / fmaxf(sqrtf(red[0]), 1e-12f);
  for (int o = t; o < 512; o += 256) out[(size_t)g * 512 + o] = ov[o] * inv;
}

// ---------------- host orchestration ----------------
extern "C" void kernel_launch(void* const* d_in, const int* in_sizes, int n_in,
                              void* d_out, int out_size, void* d_ws, size_t ws_size,
                              hipStream_t stream) {
  const int N = in_sizes[0] / 3;
  const int E = in_sizes[1] / 2;
  const int G = out_size / (2 * 512);
  const int NBUCK = (N + BUCKET_MASK) >> BUCKET_SHIFT;
  const int NB3 = (N + 255) / 256;

  char* w = (char*)d_ws;
  auto alloc = [&](size_t bytes) -> void* {
    void* p = (void*)w;
    w += (bytes + 255) & ~(size_t)255;
    return p;
  };
  float*          A        = (float*)alloc((size_t)N * 128 * 4);
  unsigned short* Abf      = (unsigned short*)alloc((size_t)N * 128 * 2);
  unsigned short* Bh       = (unsigned short*)alloc((size_t)N * 128 * 2);
  float*          dinv     = (float*)alloc((size_t)N * 4);
  float4*         xs       = (float4*)alloc((size_t)N * 16);
  float4*         ag0      = (float4*)alloc((size_t)N * 16);
  int*            rp       = (int*)alloc((size_t)(N + 1) * 4);
  int*            csr      = (int*)alloc((size_t)E * 4);
  int*            bucketed = (int*)alloc((size_t)E * 4);
  int*            bcnt     = (int*)alloc((size_t)NBUCK * 4);
  int*            bbase    = (int*)alloc((size_t)(NBUCK + 1) * 4);
  int*            bcur     = (int*)alloc((size_t)NBUCK * 4);
  float*          stats    = (float*)alloc(256 * 4);
  int*            gstart   = (int*)alloc((size_t)(G + 1) * 4);
  float*          pooled   = (float*)alloc((size_t)G * 128 * 4);
  unsigned short* Wf2      = (unsigned short*)alloc(2 * 128 * 128 * 2);
  unsigned short* Wf3      = (unsigned short*)alloc(2 * 128 * 128 * 2);
  float*          mpart    = (float*)alloc((size_t)NB3 * 9 * 4);
  float4*         W1r      = (float4*)alloc(128 * 16);
  float2*         prm      = (float2*)alloc(128 * 8);

  const float* W1  = (const float*)d_in[6];
  const float* b1  = (const float*)d_in[7];
  const float* W2  = (const float*)d_in[8];
  const float* b2  = (const float*)d_in[9];
  const float* W3  = (const float*)d_in[10];
  const float* b3  = (const float*)d_in[11];
  const float* g1  = (const float*)d_in[12];
  const float* be1 = (const float*)d_in[13];
  const float* g2  = (const float*)d_in[14];
  const float* be2 = (const float*)d_in[15];
  const float* Wp1 = (const float*)d_in[16];
  const float* bp1 = (const float*)d_in[17];
  const float* Wp2 = (const float*)d_in[18];
  const float* bp2 = (const float*)d_in[19];

  const int TB = 256;

  wsplit<<<64, TB, 0, stream>>>(W2, Wf2);
  wsplit<<<64, TB, 0, stream>>>(W3, Wf3);

  for (int br = 0; br < 2; ++br) {
    const float* x   = (const float*)d_in[br * 3 + 0];
    const int* ei    = (const int*)d_in[br * 3 + 1];
    const int* src   = ei;
    const int* dst   = ei + E;
    const int* batch = (const int*)d_in[br * 3 + 2];
    float* outp = (float*)d_out + (size_t)br * G * 512;

    zero_u32<<<(NBUCK + TB - 1) / TB, TB, 0, stream>>>((unsigned*)bcnt, NBUCK);
    bucket_count<<<256, TB, 0, stream>>>(dst, bcnt, E, NBUCK);
    bucket_scan<<<1, 1024, 0, stream>>>(bcnt, bbase, bcur, NBUCK);
    bucket_scatter2<<<(E + TILE - 1) / TILE, TB, 0, stream>>>(src, dst, bcur, bucketed, E, NBUCK);
    bucket_to_csr<<<NBUCK, TB, 0, stream>>>(bucketed, bbase, rp, dinv, csr, N, E, NBUCK);

    graph_bounds<<<(N + TB - 1) / TB, TB, 0, stream>>>(batch, gstart, N, G);

    xs_scale<<<(N + TB - 1) / TB, TB, 0, stream>>>(x, dinv, xs, N);
    agg_f3<<<NB3, TB, 0, stream>>>(xs, rp, csr, dinv, ag0, mpart, N);
    bnprep1<<<1, TB, 0, stream>>>(mpart, NB3, W1, b1, g1, be1, 1.0f / (float)N, W1r, prm);
    lin1_fused<<<(N * 128 + TB - 1) / TB, TB, 0, stream>>>(ag0, W1r, prm, Abf, N * 128);

    gemm_mfma<<<(N + 127) / 128, TB, 0, stream>>>(Abf, Wf2, dinv, Bh, N);
    agg128_bf16<<<(N + 15) / 16, TB, 0, stream>>>(Bh, rp, csr, dinv, b2, A, N);
    zero_u32<<<1, TB, 0, stream>>>((unsigned*)stats, 256);
    bn_stats<<<1024, TB, 0, stream>>>(A, stats, N);
    bn_apply_relu_bf16<<<(N * 128 + TB - 1) / TB, TB, 0, stream>>>(A, Abf, stats, g2, be2, N, 1.0f / (float)N);

    gemm_mfma<<<(N + 127) / 128, TB, 0, stream>>>(Abf, Wf3, dinv, Bh, N);
    agg128_bf16<<<(N + 15) / 16, TB, 0, stream>>>(Bh, rp, csr, dinv, b3, A, N);

    zero_u32<<<(G * 128 + TB - 1) / TB, TB, 0, stream>>>((unsigned*)pooled, G * 128);
    pool_partial<<<G * 8, TB, 0, stream>>>(A, gstart, pooled);

    mlp_kernel<<<G, TB, 0, stream>>>(pooled, gstart, Wp1, bp1, Wp2, bp2, outp);
  }
}

// Round 8
// 916.446 us; speedup vs baseline: 1.4830x; 1.1264x over previous
//
#include <hip/hip_runtime.h>
#include <math.h>

#define BUCKET_SHIFT 8            // 256 nodes per bucket
#define BUCKET_MASK 255
#define MAXBUCK 640               // supports N <= 163840
#define TILE 8192

typedef __attribute__((ext_vector_type(8))) short bf16x8;
typedef __attribute__((ext_vector_type(4))) float f32x4;

__device__ inline float bf_lo(unsigned u) { return __uint_as_float(u << 16); }
__device__ inline float bf_hi(unsigned u) { return __uint_as_float(u & 0xffff0000u); }
__device__ inline float bf2f(unsigned short s) { return __uint_as_float((unsigned)s << 16); }
__device__ inline unsigned short f2bf(float f) {   // round-to-nearest-even
  unsigned u = __float_as_uint(f);
  return (unsigned short)((u + 0x7fffu + ((u >> 16) & 1u)) >> 16);
}
__device__ inline void acc8(float* a, uint4 v) {
  a[0] += bf_lo(v.x); a[1] += bf_hi(v.x);
  a[2] += bf_lo(v.y); a[3] += bf_hi(v.y);
  a[4] += bf_lo(v.z); a[5] += bf_hi(v.z);
  a[6] += bf_lo(v.w); a[7] += bf_hi(v.w);
}
__device__ inline unsigned pack2(float a, float b) {
  return (unsigned)f2bf(a) | ((unsigned)f2bf(b) << 16);
}

// ---------------- utility ----------------
__global__ void zero_u32(unsigned int* __restrict__ p, int n) {
  int i = blockIdx.x * blockDim.x + threadIdx.x;
  if (i < n) p[i] = 0u;
}

// ---------------- bucketed CSR build ----------------
__global__ __launch_bounds__(256) void bucket_count(const int* __restrict__ dst,
                                                    int* __restrict__ bcnt, int e, int nbuck) {
  __shared__ int lc[MAXBUCK];
  for (int i = threadIdx.x; i < nbuck; i += 256) lc[i] = 0;
  __syncthreads();
  for (int i = blockIdx.x * blockDim.x + threadIdx.x; i < e; i += gridDim.x * blockDim.x)
    atomicAdd(&lc[dst[i] >> BUCKET_SHIFT], 1);
  __syncthreads();
  for (int i = threadIdx.x; i < nbuck; i += 256)
    if (lc[i]) atomicAdd(&bcnt[i], lc[i]);
}

__global__ __launch_bounds__(1024) void bucket_scan(const int* __restrict__ bcnt,
                                                    int* __restrict__ bbase,
                                                    int* __restrict__ bcur, int nbuck) {
  __shared__ int s[1024];
  int t = threadIdx.x;
  int v = (t < nbuck) ? bcnt[t] : 0;
  s[t] = v;
  __syncthreads();
  for (int off = 1; off < 1024; off <<= 1) {
    int u = (t >= off) ? s[t - off] : 0;
    __syncthreads();
    s[t] += u;
    __syncthreads();
  }
  int excl = s[t] - v;
  if (t < nbuck) {
    bbase[t] = excl;
    bcur[t] = excl;
  } else if (t == nbuck) {
    bbase[t] = excl;
  }
}

// packs edge as (src<<8)|(dst&255); bucket id kept in a side LDS array
__global__ __launch_bounds__(256) void bucket_scatter2(const int* __restrict__ src,
                                                       const int* __restrict__ dst,
                                                       int* __restrict__ bcur,
                                                       int* __restrict__ bucketed,
                                                       int e, int nbuck) {
  __shared__ int lcnt[MAXBUCK], loff[MAXBUCK], lcur[MAXBUCK], gbase[MAXBUCK];
  __shared__ int stmp[256];
  __shared__ int scarry;
  int t = threadIdx.x;
  int tile0 = blockIdx.x * TILE;
  int tn = min(TILE, e - tile0);
  __shared__ int lout[TILE];
  __shared__ unsigned short lbk[TILE];

  for (int i = t; i < nbuck; i += 256) lcnt[i] = 0;
  if (t == 0) scarry = 0;
  __syncthreads();
  for (int i = t; i < tn; i += 256)
    atomicAdd(&lcnt[dst[tile0 + i] >> BUCKET_SHIFT], 1);
  __syncthreads();
  for (int c0 = 0; c0 < nbuck; c0 += 256) {
    int idx = c0 + t;
    int v = (idx < nbuck) ? lcnt[idx] : 0;
    stmp[t] = v;
    __syncthreads();
    for (int off = 1; off < 256; off <<= 1) {
      int u = (t >= off) ? stmp[t - off] : 0;
      __syncthreads();
      stmp[t] += u;
      __syncthreads();
    }
    int excl = stmp[t] - v + scarry;
    if (idx < nbuck) { loff[idx] = excl; lcur[idx] = excl; }
    __syncthreads();
    if (t == 255) scarry += stmp[255];
    __syncthreads();
  }
  for (int i = t; i < tn; i += 256) {
    int d = dst[tile0 + i];
    int s = src[tile0 + i];
    int b = d >> BUCKET_SHIFT;
    int pos = atomicAdd(&lcur[b], 1);
    lout[pos] = (s << 8) | (d & BUCKET_MASK);
    lbk[pos] = (unsigned short)b;
  }
  __syncthreads();
  for (int i = t; i < nbuck; i += 256)
    if (lcnt[i] > 0) gbase[i] = atomicAdd(&bcur[i], lcnt[i]);
  __syncthreads();
  for (int j = t; j < tn; j += 256) {
    int b = lbk[j];
    bucketed[gbase[b] + (j - loff[b])] = lout[j];
  }
}

__global__ __launch_bounds__(256) void bucket_to_csr(const int* __restrict__ bucketed,
                                                     const int* __restrict__ bbase,
                                                     int* __restrict__ rp,
                                                     float* __restrict__ dinv,
                                                     int* __restrict__ csr,
                                                     int n, int e, int nbuck) {
  __shared__ int lcnt[256], lrp[256];
  int b = blockIdx.x, t = threadIdx.x;
  int n0 = b << BUCKET_SHIFT;
  int base = bbase[b];
  int cnt_e = bbase[b + 1] - base;
  lcnt[t] = 0;
  __syncthreads();
  for (int i = t; i < cnt_e; i += 256)
    atomicAdd(&lcnt[bucketed[base + i] & BUCKET_MASK], 1);
  __syncthreads();
  int v = lcnt[t];
  lrp[t] = v;
  __syncthreads();
  for (int off = 1; off < 256; off <<= 1) {
    int u = (t >= off) ? lrp[t - off] : 0;
    __syncthreads();
    lrp[t] += u;
    __syncthreads();
  }
  int excl = lrp[t] - v;
  int node = n0 + t;
  if (node < n) {
    rp[node] = base + excl;
    dinv[node] = rsqrtf((float)v + 1.0f);   // +1 self loop
  }
  if (b == nbuck - 1 && t == 0) rp[n] = e;
  lrp[t] = excl;
  lcnt[t] = 0;
  __syncthreads();
  for (int i = t; i < cnt_e; i += 256) {
    int ed = bucketed[base + i];
    int li = ed & BUCKET_MASK;
    int pos = atomicAdd(&lcnt[li], 1);
    csr[base + lrp[li] + pos] = (int)(((unsigned)ed) >> 8);
  }
}

// ---------------- graph boundaries from sorted batch (no atomics) ----------------
__global__ void graph_bounds(const int* __restrict__ batch, int* __restrict__ gstart,
                             int n, int g) {
  int i = blockIdx.x * blockDim.x + threadIdx.x;
  if (i >= n) return;
  int b = batch[i];
  int bp = (i == 0) ? -1 : batch[i - 1];
  for (int k = bp + 1; k <= b; ++k) gstart[k] = i;
  if (i == n - 1)
    for (int k = b + 1; k <= g; ++k) gstart[k] = n;
}

// ---------------- layer 1: pre-scale, aggregate + block moments ----------------
__global__ void xs_scale(const float* __restrict__ x, const float* __restrict__ dinv,
                         float4* __restrict__ xs, int n) {
  int i = blockIdx.x * blockDim.x + threadIdx.x;
  if (i >= n) return;
  float d = dinv[i];
  xs[i] = make_float4(x[3 * (size_t)i] * d, x[3 * (size_t)i + 1] * d,
                      x[3 * (size_t)i + 2] * d, d);
}

__global__ __launch_bounds__(256) void agg_f3(const float4* __restrict__ xs,
                                              const int* __restrict__ rp,
                                              const int* __restrict__ csr,
                                              const float* __restrict__ dinv,
                                              float4* __restrict__ out,
                                              float* __restrict__ mpart, int n) {
  int i = blockIdx.x * blockDim.x + threadIdx.x;
  int t = threadIdx.x;
  float a0 = 0.f, a1 = 0.f, a2 = 0.f;
  if (i < n) {
    float4 self = xs[i];
    a0 = self.x; a1 = self.y; a2 = self.z;
    int e0 = rp[i], e1 = rp[i + 1];
    int e = e0;
    for (; e + 4 <= e1; e += 4) {
      int s0 = csr[e], s1 = csr[e + 1], s2 = csr[e + 2], s3 = csr[e + 3];
      float4 v0 = xs[s0], v1 = xs[s1], v2 = xs[s2], v3 = xs[s3];
      a0 += (v0.x + v1.x) + (v2.x + v3.x);
      a1 += (v0.y + v1.y) + (v2.y + v3.y);
      a2 += (v0.z + v1.z) + (v2.z + v3.z);
    }
    for (; e < e1; ++e) {
      float4 v = xs[csr[e]];
      a0 += v.x; a1 += v.y; a2 += v.z;
    }
    float d = dinv[i];
    a0 *= d; a1 *= d; a2 *= d;
    out[i] = make_float4(a0, a1, a2, 0.f);
  }
  float loc[9] = {a0, a1, a2, a0 * a0, a0 * a1, a0 * a2, a1 * a1, a1 * a2, a2 * a2};
  __shared__ float red[256];
  for (int q = 0; q < 9; ++q) {
    red[t] = loc[q];
    __syncthreads();
    for (int s = 128; s > 0; s >>= 1) {
      if (t < s) red[t] += red[t + s];
      __syncthreads();
    }
    if (t == 0) mpart[blockIdx.x * 9 + q] = red[0];
    __syncthreads();
  }
}

__global__ void bnprep1(const float* __restrict__ mpart, int nblk,
                        const float* __restrict__ W1, const float* __restrict__ b1,
                        const float* __restrict__ g1, const float* __restrict__ be1,
                        float invn, float4* __restrict__ W1r, float2* __restrict__ prm) {
  __shared__ float red[256];
  __shared__ float sm[9];
  int t = threadIdx.x;
  float loc[9] = {0.f, 0.f, 0.f, 0.f, 0.f, 0.f, 0.f, 0.f, 0.f};
  for (int i = t; i < nblk; i += 256)
#pragma unroll
    for (int q = 0; q < 9; ++q) loc[q] += mpart[i * 9 + q];
  for (int q = 0; q < 9; ++q) {
    red[t] = loc[q];
    __syncthreads();
    for (int s = 128; s > 0; s >>= 1) {
      if (t < s) red[t] += red[t + s];
      __syncthreads();
    }
    if (t == 0) sm[q] = red[0] * invn;
    __syncthreads();
  }
  if (t < 128) {
    float w0 = W1[t], w1 = W1[128 + t], w2 = W1[256 + t], b = b1[t];
    float mu0 = sm[0] * w0 + sm[1] * w1 + sm[2] * w2;
    float q2 = w0 * w0 * sm[3] + w1 * w1 * sm[6] + w2 * w2 * sm[8]
             + 2.f * (w0 * w1 * sm[4] + w0 * w2 * sm[5] + w1 * w2 * sm[7]);
    float var = q2 - mu0 * mu0;
    float sc = rsqrtf(fmaxf(var, 0.f) + 1e-5f) * g1[t];
    float mu = mu0 + b;
    W1r[t] = make_float4(w0, w1, w2, b);
    prm[t] = make_float2(sc, be1[t] - mu * sc);
  }
}

__global__ void lin1_fused(const float4* __restrict__ ag, const float4* __restrict__ W1r,
                           const float2* __restrict__ prm, unsigned short* __restrict__ out,
                           int n128) {
  int idx = blockIdx.x * blockDim.x + threadIdx.x;
  if (idx >= n128) return;
  int node = idx >> 7, f = idx & 127;
  float4 a = ag[node];
  float4 w = W1r[f];
  float2 p = prm[f];
  float v = a.x * w.x + a.y * w.y + a.z * w.z + w.w;
  v = v * p.x + p.y;
  out[idx] = f2bf(fmaxf(v, 0.f));
}

// ------- W split to MFMA-fragment-major layout: hi block then lo block ----------
__global__ void wsplit(const float* __restrict__ W, unsigned short* __restrict__ Wf) {
  int i = blockIdx.x * 256 + threadIdx.x;   // 16384 = 128x128
  if (i >= 128 * 128) return;
  int k = i >> 7, f = i & 127;
  float w = W[i];                            // W[k][f]
  unsigned short hi = f2bf(w);
  float hif = __uint_as_float((unsigned)hi << 16);
  unsigned short lo = f2bf(w - hif);
  int NT = f >> 4, l15 = f & 15, ks = k >> 5, lg = (k >> 3) & 3, j = k & 7;
  int lane = lg * 16 + l15;
  size_t base = ((size_t)(NT * 4 + ks) * 64 + lane) * 8 + j;
  Wf[base] = hi;
  Wf[16384 + base] = lo;
}

// ------ MFMA GEMM (swapped operands), optional BN+ReLU applied on A-load --------
template <int BN>
__global__ __launch_bounds__(256) void gemm_mfma_t(const unsigned short* __restrict__ Abf,
                                                   const unsigned short* __restrict__ Wf,
                                                   const float* __restrict__ dinv,
                                                   const float2* __restrict__ prm,
                                                   unsigned short* __restrict__ C, int n) {
  const int t = threadIdx.x;
  const int wave = t >> 6, lane = t & 63;
  const int l15 = lane & 15, lg = lane >> 4;
  const int row0 = blockIdx.x * 128 + wave * 32;
  const int n0 = row0 + l15, n1 = row0 + 16 + l15;
  const bf16x8* wfr = (const bf16x8*)Wf;       // hi frags [0..2047], lo at +2048
  f32x4 acc[8][2] = {};
#pragma unroll
  for (int ks = 0; ks < 4; ++ks) {
    int k0 = ks * 32 + lg * 8;
    bf16x8 nf0 = {}, nf1 = {};
    if (n0 < n) nf0 = *(const bf16x8*)&Abf[(size_t)n0 * 128 + k0];
    if (n1 < n) nf1 = *(const bf16x8*)&Abf[(size_t)n1 * 128 + k0];
    if (BN) {
      float4 pa = *(const float4*)&prm[k0];
      float4 pb = *(const float4*)&prm[k0 + 2];
      float4 pc = *(const float4*)&prm[k0 + 4];
      float4 pd = *(const float4*)&prm[k0 + 6];
      float scv[8] = {pa.x, pa.z, pb.x, pb.z, pc.x, pc.z, pd.x, pd.z};
      float ofv[8] = {pa.y, pa.w, pb.y, pb.w, pc.y, pc.w, pd.y, pd.w};
#pragma unroll
      for (int j = 0; j < 8; ++j) {
        float x0 = fmaxf(bf2f((unsigned short)nf0[j]) * scv[j] + ofv[j], 0.f);
        float x1 = fmaxf(bf2f((unsigned short)nf1[j]) * scv[j] + ofv[j], 0.f);
        nf0[j] = (short)f2bf(x0);
        nf1[j] = (short)f2bf(x1);
      }
    }
#pragma unroll
    for (int NT = 0; NT < 8; ++NT) {
      bf16x8 wh = wfr[(NT * 4 + ks) * 64 + lane];
      bf16x8 wl = wfr[2048 + (NT * 4 + ks) * 64 + lane];
      acc[NT][0] = __builtin_amdgcn_mfma_f32_16x16x32_bf16(wh, nf0, acc[NT][0], 0, 0, 0);
      acc[NT][0] = __builtin_amdgcn_mfma_f32_16x16x32_bf16(wl, nf0, acc[NT][0], 0, 0, 0);
      acc[NT][1] = __builtin_amdgcn_mfma_f32_16x16x32_bf16(wh, nf1, acc[NT][1], 0, 0, 0);
      acc[NT][1] = __builtin_amdgcn_mfma_f32_16x16x32_bf16(wl, nf1, acc[NT][1], 0, 0, 0);
    }
  }
  float sc0 = (n0 < n) ? dinv[n0] : 0.f;
  float sc1 = (n1 < n) ? dinv[n1] : 0.f;
#pragma unroll
  for (int ng = 0; ng < 2; ++ng) {
    int node = (ng == 0) ? n0 : n1;
    float sc = (ng == 0) ? sc0 : sc1;
    if (node < n) {
#pragma unroll
      for (int NT = 0; NT < 8; ++NT) {
        ushort4 o;
        o.x = f2bf(acc[NT][ng][0] * sc);
        o.y = f2bf(acc[NT][ng][1] * sc);
        o.z = f2bf(acc[NT][ng][2] * sc);
        o.w = f2bf(acc[NT][ng][3] * sc);
        *(ushort4*)&C[(size_t)node * 128 + NT * 16 + lg * 4] = o;
      }
    }
  }
}

// ------- layer-2 aggregation: bf16 out + fused per-block BN partial stats -------
__global__ __launch_bounds__(256) void agg128_l2(const unsigned short* __restrict__ h,
                                                 const int* __restrict__ rp,
                                                 const int* __restrict__ csr,
                                                 const float* __restrict__ dinv,
                                                 const float* __restrict__ bias,
                                                 unsigned short* __restrict__ outb,
                                                 float* __restrict__ mpart, int n) {
  int t = threadIdx.x;
  int node = blockIdx.x * 16 + (t >> 4);
  int lane = t & 15;
  bool valid = node < n;
  const uint4* hp = (const uint4*)h;
  float acc[8] = {0.f};
  if (valid) {
    acc8(acc, hp[(size_t)node * 16 + lane]);
    int e0 = rp[node], e1 = rp[node + 1];
    int e = e0;
    for (; e + 8 <= e1; e += 8) {
      int s0 = csr[e],     s1 = csr[e + 1], s2 = csr[e + 2], s3 = csr[e + 3];
      int s4 = csr[e + 4], s5 = csr[e + 5], s6 = csr[e + 6], s7 = csr[e + 7];
      uint4 v0 = hp[(size_t)s0 * 16 + lane];
      uint4 v1 = hp[(size_t)s1 * 16 + lane];
      uint4 v2 = hp[(size_t)s2 * 16 + lane];
      uint4 v3 = hp[(size_t)s3 * 16 + lane];
      uint4 v4 = hp[(size_t)s4 * 16 + lane];
      uint4 v5 = hp[(size_t)s5 * 16 + lane];
      uint4 v6 = hp[(size_t)s6 * 16 + lane];
      uint4 v7 = hp[(size_t)s7 * 16 + lane];
      acc8(acc, v0); acc8(acc, v1); acc8(acc, v2); acc8(acc, v3);
      acc8(acc, v4); acc8(acc, v5); acc8(acc, v6); acc8(acc, v7);
    }
    for (; e + 4 <= e1; e += 4) {
      int s0 = csr[e], s1 = csr[e + 1], s2 = csr[e + 2], s3 = csr[e + 3];
      uint4 v0 = hp[(size_t)s0 * 16 + lane];
      uint4 v1 = hp[(size_t)s1 * 16 + lane];
      uint4 v2 = hp[(size_t)s2 * 16 + lane];
      uint4 v3 = hp[(size_t)s3 * 16 + lane];
      acc8(acc, v0); acc8(acc, v1); acc8(acc, v2); acc8(acc, v3);
    }
    for (; e < e1; ++e) acc8(acc, hp[(size_t)csr[e] * 16 + lane]);
  }
  float v[8], sq[8];
  if (valid) {
    float dd = dinv[node];
    float4 bb0 = *(const float4*)&bias[lane * 8];
    float4 bb1 = *(const float4*)&bias[lane * 8 + 4];
    v[0] = acc[0] * dd + bb0.x; v[1] = acc[1] * dd + bb0.y;
    v[2] = acc[2] * dd + bb0.z; v[3] = acc[3] * dd + bb0.w;
    v[4] = acc[4] * dd + bb1.x; v[5] = acc[5] * dd + bb1.y;
    v[6] = acc[6] * dd + bb1.z; v[7] = acc[7] * dd + bb1.w;
    uint4 o;
    o.x = pack2(v[0], v[1]); o.y = pack2(v[2], v[3]);
    o.z = pack2(v[4], v[5]); o.w = pack2(v[6], v[7]);
    *(uint4*)&outb[(size_t)node * 128 + lane * 8] = o;
  } else {
#pragma unroll
    for (int j = 0; j < 8; ++j) v[j] = 0.f;
  }
#pragma unroll
  for (int j = 0; j < 8; ++j) sq[j] = v[j] * v[j];
  // reduce over the wave's 4 node-groups (lanes xor 16, 32)
#pragma unroll
  for (int j = 0; j < 8; ++j) {
    v[j] += __shfl_xor(v[j], 16);  v[j] += __shfl_xor(v[j], 32);
    sq[j] += __shfl_xor(sq[j], 16); sq[j] += __shfl_xor(sq[j], 32);
  }
  __shared__ float sred[4][16][16];
  int wave = t >> 6, wl = t & 63;
  if (wl < 16) {
#pragma unroll
    for (int j = 0; j < 8; ++j) {
      sred[wave][wl][j] = v[j];
      sred[wave][wl][8 + j] = sq[j];
    }
  }
  __syncthreads();
  {
    int f = t & 127;
    int j = (f & 7) + ((t >> 7) << 3);   // 0-7 sum, 8-15 sumsq
    float s = sred[0][f >> 3][j] + sred[1][f >> 3][j]
            + sred[2][f >> 3][j] + sred[3][f >> 3][j];
    mpart[(size_t)blockIdx.x * 256 + t] = s;
  }
}

// stage-1 reduce of BN partials: 128 blocks
__global__ __launch_bounds__(256) void bnred1(const float* __restrict__ mpart, int nblk,
                                              float* __restrict__ spart) {
  int t = threadIdx.x, b = blockIdx.x;
  float loc = 0.f;
  for (int i = b; i < nblk; i += 128) loc += mpart[(size_t)i * 256 + t];
  spart[b * 256 + t] = loc;
}

// stage-2: fold 128 partials, compute per-feature (scale, offset)
__global__ void bnprep2(const float* __restrict__ spart,
                        const float* __restrict__ gam, const float* __restrict__ bet,
                        float invn, float2* __restrict__ prm) {
  int t = threadIdx.x;
  float loc = 0.f;
  for (int i = 0; i < 128; ++i) loc += spart[i * 256 + t];
  __shared__ float sm[256];
  sm[t] = loc;
  __syncthreads();
  if (t < 128) {
    float mu = sm[t] * invn;
    float var = sm[128 + t] * invn - mu * mu;
    float sc = rsqrtf(fmaxf(var, 0.f) + 1e-5f) * gam[t];
    prm[t] = make_float2(sc, bet[t] - mu * sc);
  }
}

// ------- layer-3 aggregation: bf16 out (feeds pool) ----------------------------
__global__ __launch_bounds__(256) void agg128_l3(const unsigned short* __restrict__ h,
                                                 const int* __restrict__ rp,
                                                 const int* __restrict__ csr,
                                                 const float* __restrict__ dinv,
                                                 const float* __restrict__ bias,
                                                 unsigned short* __restrict__ outb, int n) {
  int node = blockIdx.x * 16 + (threadIdx.x >> 4);
  int lane = threadIdx.x & 15;
  if (node >= n) return;
  const uint4* hp = (const uint4*)h;
  float acc[8] = {0.f};
  acc8(acc, hp[(size_t)node * 16 + lane]);
  int e0 = rp[node], e1 = rp[node + 1];
  int e = e0;
  for (; e + 8 <= e1; e += 8) {
    int s0 = csr[e],     s1 = csr[e + 1], s2 = csr[e + 2], s3 = csr[e + 3];
    int s4 = csr[e + 4], s5 = csr[e + 5], s6 = csr[e + 6], s7 = csr[e + 7];
    uint4 v0 = hp[(size_t)s0 * 16 + lane];
    uint4 v1 = hp[(size_t)s1 * 16 + lane];
    uint4 v2 = hp[(size_t)s2 * 16 + lane];
    uint4 v3 = hp[(size_t)s3 * 16 + lane];
    uint4 v4 = hp[(size_t)s4 * 16 + lane];
    uint4 v5 = hp[(size_t)s5 * 16 + lane];
    uint4 v6 = hp[(size_t)s6 * 16 + lane];
    uint4 v7 = hp[(size_t)s7 * 16 + lane];
    acc8(acc, v0); acc8(acc, v1); acc8(acc, v2); acc8(acc, v3);
    acc8(acc, v4); acc8(acc, v5); acc8(acc, v6); acc8(acc, v7);
  }
  for (; e + 4 <= e1; e += 4) {
    int s0 = csr[e], s1 = csr[e + 1], s2 = csr[e + 2], s3 = csr[e + 3];
    uint4 v0 = hp[(size_t)s0 * 16 + lane];
    uint4 v1 = hp[(size_t)s1 * 16 + lane];
    uint4 v2 = hp[(size_t)s2 * 16 + lane];
    uint4 v3 = hp[(size_t)s3 * 16 + lane];
    acc8(acc, v0); acc8(acc, v1); acc8(acc, v2); acc8(acc, v3);
  }
  for (; e < e1; ++e) acc8(acc, hp[(size_t)csr[e] * 16 + lane]);
  float dd = dinv[node];
  float4 bb0 = *(const float4*)&bias[lane * 8];
  float4 bb1 = *(const float4*)&bias[lane * 8 + 4];
  uint4 o;
  o.x = pack2(acc[0] * dd + bb0.x, acc[1] * dd + bb0.y);
  o.y = pack2(acc[2] * dd + bb0.z, acc[3] * dd + bb0.w);
  o.z = pack2(acc[4] * dd + bb1.x, acc[5] * dd + bb1.y);
  o.w = pack2(acc[6] * dd + bb1.z, acc[7] * dd + bb1.w);
  *(uint4*)&outb[(size_t)node * 128 + lane * 8] = o;
}

// ---------------- pooling (bf16 input) ----------------
__global__ void pool_partial_bf16(const unsigned short* __restrict__ z,
                                  const int* __restrict__ gstart,
                                  float* __restrict__ pooled) {
  int g = blockIdx.x >> 3, p = blockIdx.x & 7;
  int t = threadIdx.x;
  int f = t & 127, half = t >> 7;
  int beg = gstart[g], end = gstart[g + 1];
  float s = 0.f;
  for (int idx = beg + p * 2 + half; idx < end; idx += 16)
    s += bf2f(z[(size_t)idx * 128 + f]);
  __shared__ float ls[256];
  ls[t] = s;
  __syncthreads();
  if (half == 0) atomicAdd(&pooled[g * 128 + f], s + ls[t + 128]);
}

// ---------------- MLP head + L2 normalize ----------------
__global__ void mlp_kernel(const float* __restrict__ pooled, const int* __restrict__ gstart,
                           const float* __restrict__ Wp1, const float* __restrict__ bp1,
                           const float* __restrict__ Wp2, const float* __restrict__ bp2,
                           float* __restrict__ out) {
  int g = blockIdx.x, t = threadIdx.x;
  __shared__ float pv[128], hid[128], ov[512], red[256];
  if (t < 128) {
    float cntf = (float)(gstart[g + 1] - gstart[g]);
    pv[t] = pooled[g * 128 + t] / fmaxf(cntf, 1.0f);
  }
  __syncthreads();
  if (t < 128) {
    float a = bp1[t];
    for (int k = 0; k < 128; ++k) a += pv[k] * Wp1[k * 128 + t];
    hid[t] = fmaxf(a, 0.0f);
  }
  __syncthreads();
  for (int o = t; o < 512; o += 256) {
    float a = bp2[o];
    for (int k = 0; k < 128; ++k) a += hid[k] * Wp2[k * 512 + o];
    ov[o] = a;
  }
  __syncthreads();
  red[t] = ov[t] * ov[t] + ov[t + 256] * ov[t + 256];
  __syncthreads();
  for (int sdt = 128; sdt > 0; sdt >>= 1) {
    if (t < sdt) red[t] += red[t + sdt];
    __syncthreads();
  }
  float inv = 1.0f / fmaxf(sqrtf(red[0]), 1e-12f);
  for (int o = t; o < 512; o += 256) out[(size_t)g * 512 + o] = ov[o] * inv;
}

// ---------------- host orchestration ----------------
extern "C" void kernel_launch(void* const* d_in, const int* in_sizes, int n_in,
                              void* d_out, int out_size, void* d_ws, size_t ws_size,
                              hipStream_t stream) {
  const int N = in_sizes[0] / 3;
  const int E = in_sizes[1] / 2;
  const int G = out_size / (2 * 512);
  const int NBUCK = (N + BUCKET_MASK) >> BUCKET_SHIFT;
  const int NB3 = (N + 255) / 256;
  const int NAGG = (N + 15) / 16;

  char* w = (char*)d_ws;
  auto alloc = [&](size_t bytes) -> void* {
    void* p = (void*)w;
    w += (bytes + 255) & ~(size_t)255;
    return p;
  };
  unsigned short* Abf      = (unsigned short*)alloc((size_t)N * 128 * 2);
  unsigned short* Bh       = (unsigned short*)alloc((size_t)N * 128 * 2);
  float*          dinv     = (float*)alloc((size_t)N * 4);
  float4*         xs       = (float4*)alloc((size_t)N * 16);
  float4*         ag0      = (float4*)alloc((size_t)N * 16);
  int*            rp       = (int*)alloc((size_t)(N + 1) * 4);
  int*            csr      = (int*)alloc((size_t)E * 4);
  int*            bucketed = (int*)alloc((size_t)E * 4);
  int*            bcnt     = (int*)alloc((size_t)NBUCK * 4);
  int*            bbase    = (int*)alloc((size_t)(NBUCK + 1) * 4);
  int*            bcur     = (int*)alloc((size_t)NBUCK * 4);
  int*            gstart   = (int*)alloc((size_t)(G + 1) * 4);
  float*          pooled   = (float*)alloc((size_t)G * 128 * 4);
  unsigned short* Wf2      = (unsigned short*)alloc(2 * 128 * 128 * 2);
  unsigned short* Wf3      = (unsigned short*)alloc(2 * 128 * 128 * 2);
  float*          mpart    = (float*)alloc((size_t)NB3 * 9 * 4);
  float*          mpart2   = (float*)alloc((size_t)NAGG * 256 * 4);
  float*          spart    = (float*)alloc(128 * 256 * 4);
  float4*         W1r      = (float4*)alloc(128 * 16);
  float2*         prm1     = (float2*)alloc(128 * 8);
  float2*         prm2     = (float2*)alloc(128 * 8);

  const float* W1  = (const float*)d_in[6];
  const float* b1  = (const float*)d_in[7];
  const float* W2  = (const float*)d_in[8];
  const float* b2  = (const float*)d_in[9];
  const float* W3  = (const float*)d_in[10];
  const float* b3  = (const float*)d_in[11];
  const float* g1  = (const float*)d_in[12];
  const float* be1 = (const float*)d_in[13];
  const float* g2  = (const float*)d_in[14];
  const float* be2 = (const float*)d_in[15];
  const float* Wp1 = (const float*)d_in[16];
  const float* bp1 = (const float*)d_in[17];
  const float* Wp2 = (const float*)d_in[18];
  const float* bp2 = (const float*)d_in[19];

  const int TB = 256;

  wsplit<<<64, TB, 0, stream>>>(W2, Wf2);
  wsplit<<<64, TB, 0, stream>>>(W3, Wf3);

  for (int br = 0; br < 2; ++br) {
    const float* x   = (const float*)d_in[br * 3 + 0];
    const int* ei    = (const int*)d_in[br * 3 + 1];
    const int* src   = ei;
    const int* dst   = ei + E;
    const int* batch = (const int*)d_in[br * 3 + 2];
    float* outp = (float*)d_out + (size_t)br * G * 512;

    // bucketed CSR build (by dst) + degrees + rp
    zero_u32<<<(NBUCK + TB - 1) / TB, TB, 0, stream>>>((unsigned*)bcnt, NBUCK);
    bucket_count<<<256, TB, 0, stream>>>(dst, bcnt, E, NBUCK);
    bucket_scan<<<1, 1024, 0, stream>>>(bcnt, bbase, bcur, NBUCK);
    bucket_scatter2<<<(E + TILE - 1) / TILE, TB, 0, stream>>>(src, dst, bcur, bucketed, E, NBUCK);
    bucket_to_csr<<<NBUCK, TB, 0, stream>>>(bucketed, bbase, rp, dinv, csr, N, E, NBUCK);

    graph_bounds<<<(N + TB - 1) / TB, TB, 0, stream>>>(batch, gstart, N, G);

    // layer 1: pre-scale, aggregate + moments, analytic BN, fused lin+BN+ReLU
    xs_scale<<<(N + TB - 1) / TB, TB, 0, stream>>>(x, dinv, xs, N);
    agg_f3<<<NB3, TB, 0, stream>>>(xs, rp, csr, dinv, ag0, mpart, N);
    bnprep1<<<1, TB, 0, stream>>>(mpart, NB3, W1, b1, g1, be1, 1.0f / (float)N, W1r, prm1);
    lin1_fused<<<(N * 128 + TB - 1) / TB, TB, 0, stream>>>(ag0, W1r, prm1, Abf, N * 128);

    // layer 2: gemm -> agg (bf16 out + fused BN stats) -> stat reduce
    gemm_mfma_t<0><<<(N + 127) / 128, TB, 0, stream>>>(Abf, Wf2, dinv, nullptr, Bh, N);
    agg128_l2<<<NAGG, TB, 0, stream>>>(Bh, rp, csr, dinv, b2, Abf, mpart2, N);
    bnred1<<<128, TB, 0, stream>>>(mpart2, NAGG, spart);
    bnprep2<<<1, TB, 0, stream>>>(spart, g2, be2, 1.0f / (float)N, prm2);

    // layer 3: gemm with BN+ReLU fused on load -> agg (bf16 out)
    gemm_mfma_t<1><<<(N + 127) / 128, TB, 0, stream>>>(Abf, Wf3, dinv, prm2, Bh, N);
    agg128_l3<<<NAGG, TB, 0, stream>>>(Bh, rp, csr, dinv, b3, Abf, N);

    // pool (bf16 input)
    zero_u32<<<(G * 128 + TB - 1) / TB, TB, 0, stream>>>((unsigned*)pooled, G * 128);
    pool_partial_bf16<<<G * 8, TB, 0, stream>>>(Abf, gstart, pooled);

    // MLP head + normalize
    mlp_kernel<<<G, TB, 0, stream>>>(pooled, gstart, Wp1, bp1, Wp2, bp2, outp);
  }
}

// Round 9
// 828.497 us; speedup vs baseline: 1.6405x; 1.1062x over previous
//
#include <hip/hip_runtime.h>
#include <math.h>

#define BUCKET_SHIFT 8            // 256 nodes per bucket
#define BUCKET_MASK 255
#define MAXBUCK 640               // supports N <= 163840
#define TILE 8192

typedef __attribute__((ext_vector_type(8))) short bf16x8;
typedef __attribute__((ext_vector_type(4))) float f32x4;

__device__ inline float bf_lo(unsigned u) { return __uint_as_float(u << 16); }
__device__ inline float bf_hi(unsigned u) { return __uint_as_float(u & 0xffff0000u); }
__device__ inline float bf2f(unsigned short s) { return __uint_as_float((unsigned)s << 16); }
__device__ inline unsigned short f2bf(float f) {   // round-to-nearest-even
  unsigned u = __float_as_uint(f);
  return (unsigned short)((u + 0x7fffu + ((u >> 16) & 1u)) >> 16);
}
__device__ inline void acc8(float* a, uint4 v) {
  a[0] += bf_lo(v.x); a[1] += bf_hi(v.x);
  a[2] += bf_lo(v.y); a[3] += bf_hi(v.y);
  a[4] += bf_lo(v.z); a[5] += bf_hi(v.z);
  a[6] += bf_lo(v.w); a[7] += bf_hi(v.w);
}
__device__ inline unsigned pack2(float a, float b) {
  return (unsigned)f2bf(a) | ((unsigned)f2bf(b) << 16);
}

// ---------------- utility ----------------
__global__ void zero_u32(unsigned int* __restrict__ p, int n) {
  int i = blockIdx.x * blockDim.x + threadIdx.x;
  if (i < n) p[i] = 0u;
}

// ---------------- bucketed CSR build (branch-batched via blockIdx.y) ------------
__global__ __launch_bounds__(256) void bucket_count(const int* __restrict__ dst0,
                                                    const int* __restrict__ dst1,
                                                    int* __restrict__ bcnt, int e, int nbuck) {
  int br = blockIdx.y;
  const int* dst = br ? dst1 : dst0;
  bcnt += (size_t)br * nbuck;
  __shared__ int lc[MAXBUCK];
  for (int i = threadIdx.x; i < nbuck; i += 256) lc[i] = 0;
  __syncthreads();
  for (int i = blockIdx.x * blockDim.x + threadIdx.x; i < e; i += gridDim.x * blockDim.x)
    atomicAdd(&lc[dst[i] >> BUCKET_SHIFT], 1);
  __syncthreads();
  for (int i = threadIdx.x; i < nbuck; i += 256)
    if (lc[i]) atomicAdd(&bcnt[i], lc[i]);
}

__global__ __launch_bounds__(1024) void bucket_scan(const int* __restrict__ bcnt,
                                                    int* __restrict__ bbase,
                                                    int* __restrict__ bcur, int nbuck) {
  int br = blockIdx.y;
  bcnt += (size_t)br * nbuck;
  bbase += (size_t)br * (nbuck + 1);
  bcur += (size_t)br * nbuck;
  __shared__ int s[1024];
  int t = threadIdx.x;
  int v = (t < nbuck) ? bcnt[t] : 0;
  s[t] = v;
  __syncthreads();
  for (int off = 1; off < 1024; off <<= 1) {
    int u = (t >= off) ? s[t - off] : 0;
    __syncthreads();
    s[t] += u;
    __syncthreads();
  }
  int excl = s[t] - v;
  if (t < nbuck) {
    bbase[t] = excl;
    bcur[t] = excl;
  } else if (t == nbuck) {
    bbase[t] = excl;
  }
}

// rank-based scatter: no LDS staging of edges, no barrier scans (order within
// a bucket is arbitrary -> rank from LDS counters is sufficient)
__global__ __launch_bounds__(256) void bucket_scatter(const int* __restrict__ src0,
                                                      const int* __restrict__ dst0,
                                                      const int* __restrict__ src1,
                                                      const int* __restrict__ dst1,
                                                      int* __restrict__ bcur,
                                                      int* __restrict__ bucketed,
                                                      int e, int nbuck) {
  int br = blockIdx.y;
  const int* src = br ? src1 : src0;
  const int* dst = br ? dst1 : dst0;
  bcur += (size_t)br * nbuck;
  bucketed += (size_t)br * e;
  __shared__ int lcnt[MAXBUCK], gb[MAXBUCK];
  int t = threadIdx.x;
  int tile0 = blockIdx.x * TILE;
  int tn = min(TILE, e - tile0);
  for (int i = t; i < nbuck; i += 256) lcnt[i] = 0;
  __syncthreads();
  for (int i = t; i < tn; i += 256)
    atomicAdd(&lcnt[dst[tile0 + i] >> BUCKET_SHIFT], 1);
  __syncthreads();
  for (int i = t; i < nbuck; i += 256) {
    int c = lcnt[i];
    gb[i] = c ? atomicAdd(&bcur[i], c) : 0;
  }
  __syncthreads();
  for (int i = t; i < nbuck; i += 256) lcnt[i] = 0;
  __syncthreads();
  for (int i = t; i < tn; i += 256) {
    int d = dst[tile0 + i];
    int s = src[tile0 + i];
    int b = d >> BUCKET_SHIFT;
    int r = atomicAdd(&lcnt[b], 1);
    bucketed[gb[b] + r] = (s << 8) | (d & BUCKET_MASK);
  }
}

__global__ __launch_bounds__(256) void bucket_to_csr(const int* __restrict__ bucketed,
                                                     const int* __restrict__ bbase,
                                                     int* __restrict__ rp,
                                                     float* __restrict__ dinv,
                                                     int* __restrict__ csr,
                                                     int n, int e, int nbuck) {
  int br = blockIdx.y;
  bucketed += (size_t)br * e;
  bbase += (size_t)br * (nbuck + 1);
  rp += (size_t)br * (n + 1);
  dinv += (size_t)br * n;
  csr += (size_t)br * e;
  __shared__ int lcnt[256], lrp[256];
  int b = blockIdx.x, t = threadIdx.x;
  int n0 = b << BUCKET_SHIFT;
  int base = bbase[b];
  int cnt_e = bbase[b + 1] - base;
  lcnt[t] = 0;
  __syncthreads();
  for (int i = t; i < cnt_e; i += 256)
    atomicAdd(&lcnt[bucketed[base + i] & BUCKET_MASK], 1);
  __syncthreads();
  int v = lcnt[t];
  lrp[t] = v;
  __syncthreads();
  for (int off = 1; off < 256; off <<= 1) {
    int u = (t >= off) ? lrp[t - off] : 0;
    __syncthreads();
    lrp[t] += u;
    __syncthreads();
  }
  int excl = lrp[t] - v;
  int node = n0 + t;
  if (node < n) {
    rp[node] = base + excl;
    dinv[node] = rsqrtf((float)v + 1.0f);   // +1 self loop
  }
  if (b == nbuck - 1 && t == 0) rp[n] = e;
  lrp[t] = excl;
  lcnt[t] = 0;
  __syncthreads();
  for (int i = t; i < cnt_e; i += 256) {
    int ed = bucketed[base + i];
    int li = ed & BUCKET_MASK;
    int pos = atomicAdd(&lcnt[li], 1);
    csr[base + lrp[li] + pos] = (int)(((unsigned)ed) >> 8);
  }
}

// ---------------- graph boundaries from sorted batch (no atomics) ----------------
__global__ void graph_bounds(const int* __restrict__ batch0, const int* __restrict__ batch1,
                             int* __restrict__ gstart, int n, int g) {
  int br = blockIdx.y;
  const int* batch = br ? batch1 : batch0;
  gstart += (size_t)br * (g + 1);
  int i = blockIdx.x * blockDim.x + threadIdx.x;
  if (i >= n) return;
  int b = batch[i];
  int bp = (i == 0) ? -1 : batch[i - 1];
  for (int k = bp + 1; k <= b; ++k) gstart[k] = i;
  if (i == n - 1)
    for (int k = b + 1; k <= g; ++k) gstart[k] = n;
}

// ---------------- layer 1 ----------------
__global__ void xs_scale(const float* __restrict__ x0, const float* __restrict__ x1,
                         const float* __restrict__ dinv, float4* __restrict__ xs, int n) {
  int br = blockIdx.y;
  const float* x = br ? x1 : x0;
  dinv += (size_t)br * n;
  xs += (size_t)br * n;
  int i = blockIdx.x * blockDim.x + threadIdx.x;
  if (i >= n) return;
  float d = dinv[i];
  xs[i] = make_float4(x[3 * (size_t)i] * d, x[3 * (size_t)i + 1] * d,
                      x[3 * (size_t)i + 2] * d, d);
}

__global__ __launch_bounds__(256) void agg_f3(const float4* __restrict__ xs,
                                              const int* __restrict__ rp,
                                              const int* __restrict__ csr,
                                              const float* __restrict__ dinv,
                                              float4* __restrict__ out,
                                              float* __restrict__ mpart, int n, int e, int nb3) {
  int br = blockIdx.y;
  xs += (size_t)br * n;
  rp += (size_t)br * (n + 1);
  csr += (size_t)br * e;
  dinv += (size_t)br * n;
  out += (size_t)br * n;
  mpart += (size_t)br * nb3 * 9;
  int i = blockIdx.x * blockDim.x + threadIdx.x;
  int t = threadIdx.x;
  float a0 = 0.f, a1 = 0.f, a2 = 0.f;
  if (i < n) {
    float4 self = xs[i];
    a0 = self.x; a1 = self.y; a2 = self.z;
    int e0 = rp[i], e1 = rp[i + 1];
    int ee = e0;
    for (; ee + 4 <= e1; ee += 4) {
      int s0 = csr[ee], s1 = csr[ee + 1], s2 = csr[ee + 2], s3 = csr[ee + 3];
      float4 v0 = xs[s0], v1 = xs[s1], v2 = xs[s2], v3 = xs[s3];
      a0 += (v0.x + v1.x) + (v2.x + v3.x);
      a1 += (v0.y + v1.y) + (v2.y + v3.y);
      a2 += (v0.z + v1.z) + (v2.z + v3.z);
    }
    for (; ee < e1; ++ee) {
      float4 v = xs[csr[ee]];
      a0 += v.x; a1 += v.y; a2 += v.z;
    }
    float d = dinv[i];
    a0 *= d; a1 *= d; a2 *= d;
    out[i] = make_float4(a0, a1, a2, 0.f);
  }
  float loc[9] = {a0, a1, a2, a0 * a0, a0 * a1, a0 * a2, a1 * a1, a1 * a2, a2 * a2};
  __shared__ float red[256];
  for (int q = 0; q < 9; ++q) {
    red[t] = loc[q];
    __syncthreads();
    for (int s = 128; s > 0; s >>= 1) {
      if (t < s) red[t] += red[t + s];
      __syncthreads();
    }
    if (t == 0) mpart[blockIdx.x * 9 + q] = red[0];
    __syncthreads();
  }
}

__global__ void bnprep1(const float* __restrict__ mpart, int nblk,
                        const float* __restrict__ W1, const float* __restrict__ b1,
                        const float* __restrict__ g1, const float* __restrict__ be1,
                        float invn, float4* __restrict__ W1r, float2* __restrict__ prm) {
  int br = blockIdx.y;
  mpart += (size_t)br * nblk * 9;
  W1r += (size_t)br * 128;
  prm += (size_t)br * 128;
  __shared__ float red[256];
  __shared__ float sm[9];
  int t = threadIdx.x;
  float loc[9] = {0.f, 0.f, 0.f, 0.f, 0.f, 0.f, 0.f, 0.f, 0.f};
  for (int i = t; i < nblk; i += 256)
#pragma unroll
    for (int q = 0; q < 9; ++q) loc[q] += mpart[i * 9 + q];
  for (int q = 0; q < 9; ++q) {
    red[t] = loc[q];
    __syncthreads();
    for (int s = 128; s > 0; s >>= 1) {
      if (t < s) red[t] += red[t + s];
      __syncthreads();
    }
    if (t == 0) sm[q] = red[0] * invn;
    __syncthreads();
  }
  if (t < 128) {
    float w0 = W1[t], w1 = W1[128 + t], w2 = W1[256 + t], b = b1[t];
    float mu0 = sm[0] * w0 + sm[1] * w1 + sm[2] * w2;
    float q2 = w0 * w0 * sm[3] + w1 * w1 * sm[6] + w2 * w2 * sm[8]
             + 2.f * (w0 * w1 * sm[4] + w0 * w2 * sm[5] + w1 * w2 * sm[7]);
    float var = q2 - mu0 * mu0;
    float sc = rsqrtf(fmaxf(var, 0.f) + 1e-5f) * g1[t];
    float mu = mu0 + b;
    W1r[t] = make_float4(w0, w1, w2, b);
    prm[t] = make_float2(sc, be1[t] - mu * sc);
  }
}

__global__ void lin1_fused(const float4* __restrict__ ag, const float4* __restrict__ W1r,
                           const float2* __restrict__ prm, unsigned short* __restrict__ out,
                           int n) {
  int br = blockIdx.y;
  ag += (size_t)br * n;
  W1r += (size_t)br * 128;
  prm += (size_t)br * 128;
  out += (size_t)br * n * 128;
  int idx = blockIdx.x * blockDim.x + threadIdx.x;
  if (idx >= n * 128) return;
  int node = idx >> 7, f = idx & 127;
  float4 a = ag[node];
  float4 w = W1r[f];
  float2 p = prm[f];
  float v = a.x * w.x + a.y * w.y + a.z * w.z + w.w;
  v = v * p.x + p.y;
  out[idx] = f2bf(fmaxf(v, 0.f));
}

// ------- W split to MFMA-fragment-major layout (both weights in one launch) -----
__global__ void wsplit2(const float* __restrict__ W2, const float* __restrict__ W3,
                        unsigned short* __restrict__ Wf2, unsigned short* __restrict__ Wf3) {
  const float* W = blockIdx.y ? W3 : W2;
  unsigned short* Wf = blockIdx.y ? Wf3 : Wf2;
  int i = blockIdx.x * 256 + threadIdx.x;   // 16384 = 128x128
  if (i >= 128 * 128) return;
  int k = i >> 7, f = i & 127;
  float w = W[i];                            // W[k][f]
  unsigned short hi = f2bf(w);
  float hif = __uint_as_float((unsigned)hi << 16);
  unsigned short lo = f2bf(w - hif);
  int NT = f >> 4, l15 = f & 15, ks = k >> 5, lg = (k >> 3) & 3, j = k & 7;
  int lane = lg * 16 + l15;
  size_t base = ((size_t)(NT * 4 + ks) * 64 + lane) * 8 + j;
  Wf[base] = hi;
  Wf[16384 + base] = lo;
}

// ------ MFMA GEMM (swapped operands), optional BN+ReLU applied on A-load --------
template <int BN>
__global__ __launch_bounds__(256) void gemm_mfma_t(const unsigned short* __restrict__ Abf,
                                                   const unsigned short* __restrict__ Wf,
                                                   const float* __restrict__ dinv,
                                                   const float2* __restrict__ prm,
                                                   unsigned short* __restrict__ C, int n) {
  int br = blockIdx.y;
  Abf += (size_t)br * n * 128;
  dinv += (size_t)br * n;
  C += (size_t)br * n * 128;
  if (BN) prm += (size_t)br * 128;
  const int t = threadIdx.x;
  const int wave = t >> 6, lane = t & 63;
  const int l15 = lane & 15, lg = lane >> 4;
  const int row0 = blockIdx.x * 128 + wave * 32;
  const int n0 = row0 + l15, n1 = row0 + 16 + l15;
  const bf16x8* wfr = (const bf16x8*)Wf;       // hi frags [0..2047], lo at +2048
  f32x4 acc[8][2] = {};
#pragma unroll
  for (int ks = 0; ks < 4; ++ks) {
    int k0 = ks * 32 + lg * 8;
    bf16x8 nf0 = {}, nf1 = {};
    if (n0 < n) nf0 = *(const bf16x8*)&Abf[(size_t)n0 * 128 + k0];
    if (n1 < n) nf1 = *(const bf16x8*)&Abf[(size_t)n1 * 128 + k0];
    if (BN) {
      float4 pa = *(const float4*)&prm[k0];
      float4 pb = *(const float4*)&prm[k0 + 2];
      float4 pc = *(const float4*)&prm[k0 + 4];
      float4 pd = *(const float4*)&prm[k0 + 6];
      float scv[8] = {pa.x, pa.z, pb.x, pb.z, pc.x, pc.z, pd.x, pd.z};
      float ofv[8] = {pa.y, pa.w, pb.y, pb.w, pc.y, pc.w, pd.y, pd.w};
#pragma unroll
      for (int j = 0; j < 8; ++j) {
        float x0 = fmaxf(bf2f((unsigned short)nf0[j]) * scv[j] + ofv[j], 0.f);
        float x1 = fmaxf(bf2f((unsigned short)nf1[j]) * scv[j] + ofv[j], 0.f);
        nf0[j] = (short)f2bf(x0);
        nf1[j] = (short)f2bf(x1);
      }
    }
#pragma unroll
    for (int NT = 0; NT < 8; ++NT) {
      bf16x8 wh = wfr[(NT * 4 + ks) * 64 + lane];
      bf16x8 wl = wfr[2048 + (NT * 4 + ks) * 64 + lane];
      acc[NT][0] = __builtin_amdgcn_mfma_f32_16x16x32_bf16(wh, nf0, acc[NT][0], 0, 0, 0);
      acc[NT][0] = __builtin_amdgcn_mfma_f32_16x16x32_bf16(wl, nf0, acc[NT][0], 0, 0, 0);
      acc[NT][1] = __builtin_amdgcn_mfma_f32_16x16x32_bf16(wh, nf1, acc[NT][1], 0, 0, 0);
      acc[NT][1] = __builtin_amdgcn_mfma_f32_16x16x32_bf16(wl, nf1, acc[NT][1], 0, 0, 0);
    }
  }
  float sc0 = (n0 < n) ? dinv[n0] : 0.f;
  float sc1 = (n1 < n) ? dinv[n1] : 0.f;
#pragma unroll
  for (int ng = 0; ng < 2; ++ng) {
    int node = (ng == 0) ? n0 : n1;
    float sc = (ng == 0) ? sc0 : sc1;
    if (node < n) {
#pragma unroll
      for (int NT = 0; NT < 8; ++NT) {
        ushort4 o;
        o.x = f2bf(acc[NT][ng][0] * sc);
        o.y = f2bf(acc[NT][ng][1] * sc);
        o.z = f2bf(acc[NT][ng][2] * sc);
        o.w = f2bf(acc[NT][ng][3] * sc);
        *(ushort4*)&C[(size_t)node * 128 + NT * 16 + lg * 4] = o;
      }
    }
  }
}

// ------- layer-2 aggregation: bf16 out + fused per-block BN partial stats -------
__global__ __launch_bounds__(256) void agg128_l2(const unsigned short* __restrict__ h,
                                                 const int* __restrict__ rp,
                                                 const int* __restrict__ csr,
                                                 const float* __restrict__ dinv,
                                                 const float* __restrict__ bias,
                                                 unsigned short* __restrict__ outb,
                                                 float* __restrict__ mpart, int n, int e,
                                                 int nagg) {
  int br = blockIdx.y;
  h += (size_t)br * n * 128;
  rp += (size_t)br * (n + 1);
  csr += (size_t)br * e;
  dinv += (size_t)br * n;
  outb += (size_t)br * n * 128;
  mpart += (size_t)br * nagg * 256;
  int t = threadIdx.x;
  int node = blockIdx.x * 16 + (t >> 4);
  int lane = t & 15;
  bool valid = node < n;
  const uint4* hp = (const uint4*)h;
  float acc[8] = {0.f};
  if (valid) {
    acc8(acc, hp[(size_t)node * 16 + lane]);
    int e0 = rp[node], e1 = rp[node + 1];
    int ee = e0;
    for (; ee + 8 <= e1; ee += 8) {
      int s0 = csr[ee],     s1 = csr[ee + 1], s2 = csr[ee + 2], s3 = csr[ee + 3];
      int s4 = csr[ee + 4], s5 = csr[ee + 5], s6 = csr[ee + 6], s7 = csr[ee + 7];
      uint4 v0 = hp[(size_t)s0 * 16 + lane];
      uint4 v1 = hp[(size_t)s1 * 16 + lane];
      uint4 v2 = hp[(size_t)s2 * 16 + lane];
      uint4 v3 = hp[(size_t)s3 * 16 + lane];
      uint4 v4 = hp[(size_t)s4 * 16 + lane];
      uint4 v5 = hp[(size_t)s5 * 16 + lane];
      uint4 v6 = hp[(size_t)s6 * 16 + lane];
      uint4 v7 = hp[(size_t)s7 * 16 + lane];
      acc8(acc, v0); acc8(acc, v1); acc8(acc, v2); acc8(acc, v3);
      acc8(acc, v4); acc8(acc, v5); acc8(acc, v6); acc8(acc, v7);
    }
    for (; ee + 4 <= e1; ee += 4) {
      int s0 = csr[ee], s1 = csr[ee + 1], s2 = csr[ee + 2], s3 = csr[ee + 3];
      uint4 v0 = hp[(size_t)s0 * 16 + lane];
      uint4 v1 = hp[(size_t)s1 * 16 + lane];
      uint4 v2 = hp[(size_t)s2 * 16 + lane];
      uint4 v3 = hp[(size_t)s3 * 16 + lane];
      acc8(acc, v0); acc8(acc, v1); acc8(acc, v2); acc8(acc, v3);
    }
    for (; ee < e1; ++ee) acc8(acc, hp[(size_t)csr[ee] * 16 + lane]);
  }
  float v[8], sq[8];
  if (valid) {
    float dd = dinv[node];
    float4 bb0 = *(const float4*)&bias[lane * 8];
    float4 bb1 = *(const float4*)&bias[lane * 8 + 4];
    v[0] = acc[0] * dd + bb0.x; v[1] = acc[1] * dd + bb0.y;
    v[2] = acc[2] * dd + bb0.z; v[3] = acc[3] * dd + bb0.w;
    v[4] = acc[4] * dd + bb1.x; v[5] = acc[5] * dd + bb1.y;
    v[6] = acc[6] * dd + bb1.z; v[7] = acc[7] * dd + bb1.w;
    uint4 o;
    o.x = pack2(v[0], v[1]); o.y = pack2(v[2], v[3]);
    o.z = pack2(v[4], v[5]); o.w = pack2(v[6], v[7]);
    *(uint4*)&outb[(size_t)node * 128 + lane * 8] = o;
  } else {
#pragma unroll
    for (int j = 0; j < 8; ++j) v[j] = 0.f;
  }
#pragma unroll
  for (int j = 0; j < 8; ++j) sq[j] = v[j] * v[j];
#pragma unroll
  for (int j = 0; j < 8; ++j) {
    v[j] += __shfl_xor(v[j], 16);  v[j] += __shfl_xor(v[j], 32);
    sq[j] += __shfl_xor(sq[j], 16); sq[j] += __shfl_xor(sq[j], 32);
  }
  __shared__ float sred[4][16][16];
  int wave = t >> 6, wl = t & 63;
  if (wl < 16) {
#pragma unroll
    for (int j = 0; j < 8; ++j) {
      sred[wave][wl][j] = v[j];
      sred[wave][wl][8 + j] = sq[j];
    }
  }
  __syncthreads();
  {
    int f = t & 127;
    int j = (f & 7) + ((t >> 7) << 3);   // 0-7 sum, 8-15 sumsq
    float s = sred[0][f >> 3][j] + sred[1][f >> 3][j]
            + sred[2][f >> 3][j] + sred[3][f >> 3][j];
    mpart[(size_t)blockIdx.x * 256 + t] = s;
  }
}

// stage-1 reduce of BN partials
__global__ __launch_bounds__(256) void bnred1(const float* __restrict__ mpart, int nblk,
                                              float* __restrict__ spart) {
  int br = blockIdx.y;
  mpart += (size_t)br * nblk * 256;
  spart += (size_t)br * 128 * 256;
  int t = threadIdx.x, b = blockIdx.x;
  float loc = 0.f;
  for (int i = b; i < nblk; i += 128) loc += mpart[(size_t)i * 256 + t];
  spart[b * 256 + t] = loc;
}

// stage-2: fold partials, compute per-feature (scale, offset)
__global__ void bnprep2(const float* __restrict__ spart,
                        const float* __restrict__ gam, const float* __restrict__ bet,
                        float invn, float2* __restrict__ prm) {
  int br = blockIdx.y;
  spart += (size_t)br * 128 * 256;
  prm += (size_t)br * 128;
  int t = threadIdx.x;
  float loc = 0.f;
  for (int i = 0; i < 128; ++i) loc += spart[i * 256 + t];
  __shared__ float sm[256];
  sm[t] = loc;
  __syncthreads();
  if (t < 128) {
    float mu = sm[t] * invn;
    float var = sm[128 + t] * invn - mu * mu;
    float sc = rsqrtf(fmaxf(var, 0.f) + 1e-5f) * gam[t];
    prm[t] = make_float2(sc, bet[t] - mu * sc);
  }
}

// ------- layer-3 aggregation: bf16 out (feeds pool) ----------------------------
__global__ __launch_bounds__(256) void agg128_l3(const unsigned short* __restrict__ h,
                                                 const int* __restrict__ rp,
                                                 const int* __restrict__ csr,
                                                 const float* __restrict__ dinv,
                                                 const float* __restrict__ bias,
                                                 unsigned short* __restrict__ outb,
                                                 int n, int e) {
  int br = blockIdx.y;
  h += (size_t)br * n * 128;
  rp += (size_t)br * (n + 1);
  csr += (size_t)br * e;
  dinv += (size_t)br * n;
  outb += (size_t)br * n * 128;
  int node = blockIdx.x * 16 + (threadIdx.x >> 4);
  int lane = threadIdx.x & 15;
  if (node >= n) return;
  const uint4* hp = (const uint4*)h;
  float acc[8] = {0.f};
  acc8(acc, hp[(size_t)node * 16 + lane]);
  int e0 = rp[node], e1 = rp[node + 1];
  int ee = e0;
  for (; ee + 8 <= e1; ee += 8) {
    int s0 = csr[ee],     s1 = csr[ee + 1], s2 = csr[ee + 2], s3 = csr[ee + 3];
    int s4 = csr[ee + 4], s5 = csr[ee + 5], s6 = csr[ee + 6], s7 = csr[ee + 7];
    uint4 v0 = hp[(size_t)s0 * 16 + lane];
    uint4 v1 = hp[(size_t)s1 * 16 + lane];
    uint4 v2 = hp[(size_t)s2 * 16 + lane];
    uint4 v3 = hp[(size_t)s3 * 16 + lane];
    uint4 v4 = hp[(size_t)s4 * 16 + lane];
    uint4 v5 = hp[(size_t)s5 * 16 + lane];
    uint4 v6 = hp[(size_t)s6 * 16 + lane];
    uint4 v7 = hp[(size_t)s7 * 16 + lane];
    acc8(acc, v0); acc8(acc, v1); acc8(acc, v2); acc8(acc, v3);
    acc8(acc, v4); acc8(acc, v5); acc8(acc, v6); acc8(acc, v7);
  }
  for (; ee + 4 <= e1; ee += 4) {
    int s0 = csr[ee], s1 = csr[ee + 1], s2 = csr[ee + 2], s3 = csr[ee + 3];
    uint4 v0 = hp[(size_t)s0 * 16 + lane];
    uint4 v1 = hp[(size_t)s1 * 16 + lane];
    uint4 v2 = hp[(size_t)s2 * 16 + lane];
    uint4 v3 = hp[(size_t)s3 * 16 + lane];
    acc8(acc, v0); acc8(acc, v1); acc8(acc, v2); acc8(acc, v3);
  }
  for (; ee < e1; ++ee) acc8(acc, hp[(size_t)csr[ee] * 16 + lane]);
  float dd = dinv[node];
  float4 bb0 = *(const float4*)&bias[lane * 8];
  float4 bb1 = *(const float4*)&bias[lane * 8 + 4];
  uint4 o;
  o.x = pack2(acc[0] * dd + bb0.x, acc[1] * dd + bb0.y);
  o.y = pack2(acc[2] * dd + bb0.z, acc[3] * dd + bb0.w);
  o.z = pack2(acc[4] * dd + bb1.x, acc[5] * dd + bb1.y);
  o.w = pack2(acc[6] * dd + bb1.z, acc[7] * dd + bb1.w);
  *(uint4*)&outb[(size_t)node * 128 + lane * 8] = o;
}

// ---------------- pooling (bf16 input) ----------------
__global__ void pool_partial_bf16(const unsigned short* __restrict__ z,
                                  const int* __restrict__ gstart,
                                  float* __restrict__ pooled, int n, int g) {
  int br = blockIdx.y;
  z += (size_t)br * n * 128;
  gstart += (size_t)br * (g + 1);
  pooled += (size_t)br * g * 128;
  int gg = blockIdx.x >> 3, p = blockIdx.x & 7;
  int t = threadIdx.x;
  int f = t & 127, half = t >> 7;
  int beg = gstart[gg], end = gstart[gg + 1];
  float s = 0.f;
  for (int idx = beg + p * 2 + half; idx < end; idx += 16)
    s += bf2f(z[(size_t)idx * 128 + f]);
  __shared__ float ls[256];
  ls[t] = s;
  __syncthreads();
  if (half == 0) atomicAdd(&pooled[gg * 128 + f], s + ls[t + 128]);
}

// ---------------- MLP head + L2 normalize ----------------
__global__ void mlp_kernel(const float* __restrict__ pooled, const int* __restrict__ gstart,
                           const float* __restrict__ Wp1, const float* __restrict__ bp1,
                           const float* __restrict__ Wp2, const float* __restrict__ bp2,
                           float* __restrict__ out, int g) {
  int br = blockIdx.y;
  pooled += (size_t)br * g * 128;
  gstart += (size_t)br * (g + 1);
  out += (size_t)br * g * 512;
  int gg = blockIdx.x, t = threadIdx.x;
  __shared__ float pv[128], hid[128], ov[512], red[256];
  if (t < 128) {
    float cntf = (float)(gstart[gg + 1] - gstart[gg]);
    pv[t] = pooled[gg * 128 + t] / fmaxf(cntf, 1.0f);
  }
  __syncthreads();
  if (t < 128) {
    float a = bp1[t];
    for (int k = 0; k < 128; ++k) a += pv[k] * Wp1[k * 128 + t];
    hid[t] = fmaxf(a, 0.0f);
  }
  __syncthreads();
  for (int o = t; o < 512; o += 256) {
    float a = bp2[o];
    for (int k = 0; k < 128; ++k) a += hid[k] * Wp2[k * 512 + o];
    ov[o] = a;
  }
  __syncthreads();
  red[t] = ov[t] * ov[t] + ov[t + 256] * ov[t + 256];
  __syncthreads();
  for (int sdt = 128; sdt > 0; sdt >>= 1) {
    if (t < sdt) red[t] += red[t + sdt];
    __syncthreads();
  }
  float inv = 1.0f / fmaxf(sqrtf(red[0]), 1e-12f);
  for (int o = t; o < 512; o += 256) out[(size_t)gg * 512 + o] = ov[o] * inv;
}

// ---------------- host orchestration ----------------
extern "C" void kernel_launch(void* const* d_in, const int* in_sizes, int n_in,
                              void* d_out, int out_size, void* d_ws, size_t ws_size,
                              hipStream_t stream) {
  const int N = in_sizes[0] / 3;
  const int E = in_sizes[1] / 2;
  const int G = out_size / (2 * 512);
  const int NBUCK = (N + BUCKET_MASK) >> BUCKET_SHIFT;
  const int NB3 = (N + 255) / 256;
  const int NAGG = (N + 15) / 16;

  char* w = (char*)d_ws;
  auto alloc = [&](size_t bytes) -> void* {
    void* p = (void*)w;
    w += (bytes + 255) & ~(size_t)255;
    return p;
  };
  // all per-branch buffers allocated 2x, kernel offsets by blockIdx.y
  unsigned short* Abf      = (unsigned short*)alloc(2 * (size_t)N * 128 * 2);
  unsigned short* Bh       = (unsigned short*)alloc(2 * (size_t)N * 128 * 2);
  float*          dinv     = (float*)alloc(2 * (size_t)N * 4);
  float4*         xs       = (float4*)alloc(2 * (size_t)N * 16);
  float4*         ag0      = (float4*)alloc(2 * (size_t)N * 16);
  int*            rp       = (int*)alloc(2 * (size_t)(N + 1) * 4);
  int*            csr      = (int*)alloc(2 * (size_t)E * 4);
  int*            bucketed = (int*)alloc(2 * (size_t)E * 4);
  int*            bcnt     = (int*)alloc(2 * (size_t)NBUCK * 4);
  int*            bbase    = (int*)alloc(2 * (size_t)(NBUCK + 1) * 4);
  int*            bcur     = (int*)alloc(2 * (size_t)NBUCK * 4);
  int*            gstart   = (int*)alloc(2 * (size_t)(G + 1) * 4);
  float*          pooled   = (float*)alloc(2 * (size_t)G * 128 * 4);
  unsigned short* Wf2      = (unsigned short*)alloc(2 * 128 * 128 * 2);
  unsigned short* Wf3      = (unsigned short*)alloc(2 * 128 * 128 * 2);
  float*          mpart    = (float*)alloc(2 * (size_t)NB3 * 9 * 4);
  float*          mpart2   = (float*)alloc(2 * (size_t)NAGG * 256 * 4);
  float*          spart    = (float*)alloc(2 * (size_t)128 * 256 * 4);
  float4*         W1r      = (float4*)alloc(2 * 128 * 16);
  float2*         prm1     = (float2*)alloc(2 * 128 * 8);
  float2*         prm2     = (float2*)alloc(2 * 128 * 8);

  const float* x0    = (const float*)d_in[0];
  const int*   ei0   = (const int*)d_in[1];
  const int*   bat0  = (const int*)d_in[2];
  const float* x1    = (const float*)d_in[3];
  const int*   ei1   = (const int*)d_in[4];
  const int*   bat1  = (const int*)d_in[5];
  const float* W1  = (const float*)d_in[6];
  const float* b1  = (const float*)d_in[7];
  const float* W2  = (const float*)d_in[8];
  const float* b2  = (const float*)d_in[9];
  const float* W3  = (const float*)d_in[10];
  const float* b3  = (const float*)d_in[11];
  const float* g1  = (const float*)d_in[12];
  const float* be1 = (const float*)d_in[13];
  const float* g2  = (const float*)d_in[14];
  const float* be2 = (const float*)d_in[15];
  const float* Wp1 = (const float*)d_in[16];
  const float* bp1 = (const float*)d_in[17];
  const float* Wp2 = (const float*)d_in[18];
  const float* bp2 = (const float*)d_in[19];

  const int* src0 = ei0;
  const int* dst0 = ei0 + E;
  const int* src1 = ei1;
  const int* dst1 = ei1 + E;
  float* outp = (float*)d_out;

  const int TB = 256;
  const int NTILE = (E + TILE - 1) / TILE;
  const float invn = 1.0f / (float)N;

  wsplit2<<<dim3(64, 2), TB, 0, stream>>>(W2, W3, Wf2, Wf3);

  // CSR build (both branches batched)
  zero_u32<<<(2 * NBUCK + TB - 1) / TB, TB, 0, stream>>>((unsigned*)bcnt, 2 * NBUCK);
  bucket_count<<<dim3(256, 2), TB, 0, stream>>>(dst0, dst1, bcnt, E, NBUCK);
  bucket_scan<<<dim3(1, 2), 1024, 0, stream>>>(bcnt, bbase, bcur, NBUCK);
  bucket_scatter<<<dim3(NTILE, 2), TB, 0, stream>>>(src0, dst0, src1, dst1, bcur, bucketed, E, NBUCK);
  bucket_to_csr<<<dim3(NBUCK, 2), TB, 0, stream>>>(bucketed, bbase, rp, dinv, csr, N, E, NBUCK);

  graph_bounds<<<dim3((N + TB - 1) / TB, 2), TB, 0, stream>>>(bat0, bat1, gstart, N, G);

  // layer 1
  xs_scale<<<dim3((N + TB - 1) / TB, 2), TB, 0, stream>>>(x0, x1, dinv, xs, N);
  agg_f3<<<dim3(NB3, 2), TB, 0, stream>>>(xs, rp, csr, dinv, ag0, mpart, N, E, NB3);
  bnprep1<<<dim3(1, 2), TB, 0, stream>>>(mpart, NB3, W1, b1, g1, be1, invn, W1r, prm1);
  lin1_fused<<<dim3((N * 128 + TB - 1) / TB, 2), TB, 0, stream>>>(ag0, W1r, prm1, Abf, N);

  // layer 2
  gemm_mfma_t<0><<<dim3((N + 127) / 128, 2), TB, 0, stream>>>(Abf, Wf2, dinv, nullptr, Bh, N);
  agg128_l2<<<dim3(NAGG, 2), TB, 0, stream>>>(Bh, rp, csr, dinv, b2, Abf, mpart2, N, E, NAGG);
  bnred1<<<dim3(128, 2), TB, 0, stream>>>(mpart2, NAGG, spart);
  bnprep2<<<dim3(1, 2), TB, 0, stream>>>(spart, g2, be2, invn, prm2);

  // layer 3
  gemm_mfma_t<1><<<dim3((N + 127) / 128, 2), TB, 0, stream>>>(Abf, Wf3, dinv, prm2, Bh, N);
  agg128_l3<<<dim3(NAGG, 2), TB, 0, stream>>>(Bh, rp, csr, dinv, b3, Abf, N, E);

  // pool + head
  zero_u32<<<(2 * G * 128 + TB - 1) / TB, TB, 0, stream>>>((unsigned*)pooled, 2 * G * 128);
  pool_partial_bf16<<<dim3(G * 8, 2), TB, 0, stream>>>(Abf, gstart, pooled, N, G);
  mlp_kernel<<<dim3(G, 2), TB, 0, stream>>>(pooled, gstart, Wp1, bp1, Wp2, bp2, outp, G);
}

// Round 10
// 727.212 us; speedup vs baseline: 1.8689x; 1.1393x over previous
//
#include <hip/hip_runtime.h>
#include <math.h>

#define BUCKET_SHIFT 8            // 256 nodes per bucket
#define BUCKET_MASK 255
#define MAXBUCK 640               // supports N <= 163840
#define TILE 8192

typedef __attribute__((ext_vector_type(8))) short bf16x8;
typedef __attribute__((ext_vector_type(4))) float f32x4;

__device__ inline float bf_lo(unsigned u) { return __uint_as_float(u << 16); }
__device__ inline float bf_hi(unsigned u) { return __uint_as_float(u & 0xffff0000u); }
__device__ inline float bf2f(unsigned short s) { return __uint_as_float((unsigned)s << 16); }
__device__ inline unsigned short f2bf(float f) {   // round-to-nearest-even
  unsigned u = __float_as_uint(f);
  return (unsigned short)((u + 0x7fffu + ((u >> 16) & 1u)) >> 16);
}
__device__ inline void acc8(float* a, uint4 v) {
  a[0] += bf_lo(v.x); a[1] += bf_hi(v.x);
  a[2] += bf_lo(v.y); a[3] += bf_hi(v.y);
  a[4] += bf_lo(v.z); a[5] += bf_hi(v.z);
  a[6] += bf_lo(v.w); a[7] += bf_hi(v.w);
}
__device__ inline unsigned pack2(float a, float b) {
  return (unsigned)f2bf(a) | ((unsigned)f2bf(b) << 16);
}

// ---------------- utility ----------------
__global__ void zero_u32(unsigned int* __restrict__ p, int n) {
  int i = blockIdx.x * blockDim.x + threadIdx.x;
  if (i < n) p[i] = 0u;
}

// ---------------- bucketed CSR build (branch-batched via blockIdx.y) ------------
__global__ __launch_bounds__(256) void bucket_count(const int* __restrict__ dst0,
                                                    const int* __restrict__ dst1,
                                                    int* __restrict__ bcnt, int e, int nbuck) {
  int br = blockIdx.y;
  const int* dst = br ? dst1 : dst0;
  bcnt += (size_t)br * nbuck;
  __shared__ int lc[MAXBUCK];
  for (int i = threadIdx.x; i < nbuck; i += 256) lc[i] = 0;
  __syncthreads();
  for (int i = blockIdx.x * blockDim.x + threadIdx.x; i < e; i += gridDim.x * blockDim.x)
    atomicAdd(&lc[dst[i] >> BUCKET_SHIFT], 1);
  __syncthreads();
  for (int i = threadIdx.x; i < nbuck; i += 256)
    if (lc[i]) atomicAdd(&bcnt[i], lc[i]);
}

__global__ __launch_bounds__(1024) void bucket_scan(const int* __restrict__ bcnt,
                                                    int* __restrict__ bbase,
                                                    int* __restrict__ bcur, int nbuck) {
  int br = blockIdx.y;
  bcnt += (size_t)br * nbuck;
  bbase += (size_t)br * (nbuck + 1);
  bcur += (size_t)br * nbuck;
  __shared__ int s[1024];
  int t = threadIdx.x;
  int v = (t < nbuck) ? bcnt[t] : 0;
  s[t] = v;
  __syncthreads();
  for (int off = 1; off < 1024; off <<= 1) {
    int u = (t >= off) ? s[t - off] : 0;
    __syncthreads();
    s[t] += u;
    __syncthreads();
  }
  int excl = s[t] - v;
  if (t < nbuck) {
    bbase[t] = excl;
    bcur[t] = excl;
  } else if (t == nbuck) {
    bbase[t] = excl;
  }
}

// rank-based scatter (order within a bucket is arbitrary)
__global__ __launch_bounds__(256) void bucket_scatter(const int* __restrict__ src0,
                                                      const int* __restrict__ dst0,
                                                      const int* __restrict__ src1,
                                                      const int* __restrict__ dst1,
                                                      int* __restrict__ bcur,
                                                      int* __restrict__ bucketed,
                                                      int e, int nbuck) {
  int br = blockIdx.y;
  const int* src = br ? src1 : src0;
  const int* dst = br ? dst1 : dst0;
  bcur += (size_t)br * nbuck;
  bucketed += (size_t)br * e;
  __shared__ int lcnt[MAXBUCK], gb[MAXBUCK];
  int t = threadIdx.x;
  int tile0 = blockIdx.x * TILE;
  int tn = min(TILE, e - tile0);
  for (int i = t; i < nbuck; i += 256) lcnt[i] = 0;
  __syncthreads();
  for (int i = t; i < tn; i += 256)
    atomicAdd(&lcnt[dst[tile0 + i] >> BUCKET_SHIFT], 1);
  __syncthreads();
  for (int i = t; i < nbuck; i += 256) {
    int c = lcnt[i];
    gb[i] = c ? atomicAdd(&bcur[i], c) : 0;
  }
  __syncthreads();
  for (int i = t; i < nbuck; i += 256) lcnt[i] = 0;
  __syncthreads();
  for (int i = t; i < tn; i += 256) {
    int d = dst[tile0 + i];
    int s = src[tile0 + i];
    int b = d >> BUCKET_SHIFT;
    int r = atomicAdd(&lcnt[b], 1);
    bucketed[gb[b] + r] = (s << 8) | (d & BUCKET_MASK);
  }
}

__global__ __launch_bounds__(256) void bucket_to_csr(const int* __restrict__ bucketed,
                                                     const int* __restrict__ bbase,
                                                     int* __restrict__ rp,
                                                     float* __restrict__ dinv,
                                                     int* __restrict__ csr,
                                                     int n, int e, int nbuck) {
  int br = blockIdx.y;
  bucketed += (size_t)br * e;
  bbase += (size_t)br * (nbuck + 1);
  rp += (size_t)br * (n + 1);
  dinv += (size_t)br * n;
  csr += (size_t)br * e;
  __shared__ int lcnt[256], lrp[256];
  int b = blockIdx.x, t = threadIdx.x;
  int n0 = b << BUCKET_SHIFT;
  int base = bbase[b];
  int cnt_e = bbase[b + 1] - base;
  lcnt[t] = 0;
  __syncthreads();
  for (int i = t; i < cnt_e; i += 256)
    atomicAdd(&lcnt[bucketed[base + i] & BUCKET_MASK], 1);
  __syncthreads();
  int v = lcnt[t];
  lrp[t] = v;
  __syncthreads();
  for (int off = 1; off < 256; off <<= 1) {
    int u = (t >= off) ? lrp[t - off] : 0;
    __syncthreads();
    lrp[t] += u;
    __syncthreads();
  }
  int excl = lrp[t] - v;
  int node = n0 + t;
  if (node < n) {
    rp[node] = base + excl;
    dinv[node] = rsqrtf((float)v + 1.0f);   // +1 self loop
  }
  if (b == nbuck - 1 && t == 0) rp[n] = e;
  lrp[t] = excl;
  lcnt[t] = 0;
  __syncthreads();
  for (int i = t; i < cnt_e; i += 256) {
    int ed = bucketed[base + i];
    int li = ed & BUCKET_MASK;
    int pos = atomicAdd(&lcnt[li], 1);
    csr[base + lrp[li] + pos] = (int)(((unsigned)ed) >> 8);
  }
}

// ---------------- graph boundaries from sorted batch (no atomics) ----------------
__global__ void graph_bounds(const int* __restrict__ batch0, const int* __restrict__ batch1,
                             int* __restrict__ gstart, int n, int g) {
  int br = blockIdx.y;
  const int* batch = br ? batch1 : batch0;
  gstart += (size_t)br * (g + 1);
  int i = blockIdx.x * blockDim.x + threadIdx.x;
  if (i >= n) return;
  int b = batch[i];
  int bp = (i == 0) ? -1 : batch[i - 1];
  for (int k = bp + 1; k <= b; ++k) gstart[k] = i;
  if (i == n - 1)
    for (int k = b + 1; k <= g; ++k) gstart[k] = n;
}

// ---------------- layer 1 ----------------
__global__ void xs_scale(const float* __restrict__ x0, const float* __restrict__ x1,
                         const float* __restrict__ dinv, float4* __restrict__ xs, int n) {
  int br = blockIdx.y;
  const float* x = br ? x1 : x0;
  dinv += (size_t)br * n;
  xs += (size_t)br * n;
  int i = blockIdx.x * blockDim.x + threadIdx.x;
  if (i >= n) return;
  float d = dinv[i];
  xs[i] = make_float4(x[3 * (size_t)i] * d, x[3 * (size_t)i + 1] * d,
                      x[3 * (size_t)i + 2] * d, d);
}

__global__ __launch_bounds__(256) void agg_f3(const float4* __restrict__ xs,
                                              const int* __restrict__ rp,
                                              const int* __restrict__ csr,
                                              const float* __restrict__ dinv,
                                              float4* __restrict__ out,
                                              float* __restrict__ mpart, int n, int e, int nb3) {
  int br = blockIdx.y;
  xs += (size_t)br * n;
  rp += (size_t)br * (n + 1);
  csr += (size_t)br * e;
  dinv += (size_t)br * n;
  out += (size_t)br * n;
  mpart += (size_t)br * nb3 * 9;
  int i = blockIdx.x * blockDim.x + threadIdx.x;
  int t = threadIdx.x;
  float a0 = 0.f, a1 = 0.f, a2 = 0.f;
  if (i < n) {
    float4 self = xs[i];
    a0 = self.x; a1 = self.y; a2 = self.z;
    int e0 = rp[i], e1 = rp[i + 1];
    int ee = e0;
    for (; ee + 4 <= e1; ee += 4) {
      int s0 = csr[ee], s1 = csr[ee + 1], s2 = csr[ee + 2], s3 = csr[ee + 3];
      float4 v0 = xs[s0], v1 = xs[s1], v2 = xs[s2], v3 = xs[s3];
      a0 += (v0.x + v1.x) + (v2.x + v3.x);
      a1 += (v0.y + v1.y) + (v2.y + v3.y);
      a2 += (v0.z + v1.z) + (v2.z + v3.z);
    }
    for (; ee < e1; ++ee) {
      float4 v = xs[csr[ee]];
      a0 += v.x; a1 += v.y; a2 += v.z;
    }
    float d = dinv[i];
    a0 *= d; a1 *= d; a2 *= d;
    out[i] = make_float4(a0, a1, a2, 0.f);
  }
  float loc[9] = {a0, a1, a2, a0 * a0, a0 * a1, a0 * a2, a1 * a1, a1 * a2, a2 * a2};
  __shared__ float red[256];
  for (int q = 0; q < 9; ++q) {
    red[t] = loc[q];
    __syncthreads();
    for (int s = 128; s > 0; s >>= 1) {
      if (t < s) red[t] += red[t + s];
      __syncthreads();
    }
    if (t == 0) mpart[blockIdx.x * 9 + q] = red[0];
    __syncthreads();
  }
}

__global__ void bnprep1(const float* __restrict__ mpart, int nblk,
                        const float* __restrict__ W1, const float* __restrict__ b1,
                        const float* __restrict__ g1, const float* __restrict__ be1,
                        float invn, float4* __restrict__ W1r, float2* __restrict__ prm) {
  int br = blockIdx.y;
  mpart += (size_t)br * nblk * 9;
  W1r += (size_t)br * 128;
  prm += (size_t)br * 128;
  __shared__ float red[256];
  __shared__ float sm[9];
  int t = threadIdx.x;
  float loc[9] = {0.f, 0.f, 0.f, 0.f, 0.f, 0.f, 0.f, 0.f, 0.f};
  for (int i = t; i < nblk; i += 256)
#pragma unroll
    for (int q = 0; q < 9; ++q) loc[q] += mpart[i * 9 + q];
  for (int q = 0; q < 9; ++q) {
    red[t] = loc[q];
    __syncthreads();
    for (int s = 128; s > 0; s >>= 1) {
      if (t < s) red[t] += red[t + s];
      __syncthreads();
    }
    if (t == 0) sm[q] = red[0] * invn;
    __syncthreads();
  }
  if (t < 128) {
    float w0 = W1[t], w1 = W1[128 + t], w2 = W1[256 + t], b = b1[t];
    float mu0 = sm[0] * w0 + sm[1] * w1 + sm[2] * w2;
    float q2 = w0 * w0 * sm[3] + w1 * w1 * sm[6] + w2 * w2 * sm[8]
             + 2.f * (w0 * w1 * sm[4] + w0 * w2 * sm[5] + w1 * w2 * sm[7]);
    float var = q2 - mu0 * mu0;
    float sc = rsqrtf(fmaxf(var, 0.f) + 1e-5f) * g1[t];
    float mu = mu0 + b;
    W1r[t] = make_float4(w0, w1, w2, b);
    prm[t] = make_float2(sc, be1[t] - mu * sc);
  }
}

// ------- W split to MFMA-fragment-major layout (both weights in one launch) -----
__global__ void wsplit2(const float* __restrict__ W2, const float* __restrict__ W3,
                        unsigned short* __restrict__ Wf2, unsigned short* __restrict__ Wf3) {
  const float* W = blockIdx.y ? W3 : W2;
  unsigned short* Wf = blockIdx.y ? Wf3 : Wf2;
  int i = blockIdx.x * 256 + threadIdx.x;   // 16384 = 128x128
  if (i >= 128 * 128) return;
  int k = i >> 7, f = i & 127;
  float w = W[i];                            // W[k][f]
  unsigned short hi = f2bf(w);
  float hif = __uint_as_float((unsigned)hi << 16);
  unsigned short lo = f2bf(w - hif);
  int NT = f >> 4, l15 = f & 15, ks = k >> 5, lg = (k >> 3) & 3, j = k & 7;
  int lane = lg * 16 + l15;
  size_t base = ((size_t)(NT * 4 + ks) * 64 + lane) * 8 + j;
  Wf[base] = hi;
  Wf[16384 + base] = lo;
}

// ------ MFMA GEMM (swapped operands)
// MODE 1: BN+ReLU applied to bf16 A on load (layer 3)
// MODE 2: A computed on-the-fly from ag0 via fused lin1+BN+ReLU (layer 2)
template <int MODE>
__global__ __launch_bounds__(256) void gemm_mfma_t(const unsigned short* __restrict__ Abf,
                                                   const float4* __restrict__ ag0,
                                                   const float4* __restrict__ W1r,
                                                   const unsigned short* __restrict__ Wf,
                                                   const float* __restrict__ dinv,
                                                   const float2* __restrict__ prm,
                                                   unsigned short* __restrict__ C, int n) {
  int br = blockIdx.y;
  if (MODE == 1) Abf += (size_t)br * n * 128;
  if (MODE == 2) { ag0 += (size_t)br * n; W1r += (size_t)br * 128; }
  dinv += (size_t)br * n;
  C += (size_t)br * n * 128;
  prm += (size_t)br * 128;
  const int t = threadIdx.x;
  const int wave = t >> 6, lane = t & 63;
  const int l15 = lane & 15, lg = lane >> 4;
  const int row0 = blockIdx.x * 128 + wave * 32;
  const int n0 = row0 + l15, n1 = row0 + 16 + l15;
  const bf16x8* wfr = (const bf16x8*)Wf;       // hi frags [0..2047], lo at +2048
  float4 a0v = make_float4(0.f, 0.f, 0.f, 0.f), a1v = a0v;
  if (MODE == 2) {
    if (n0 < n) a0v = ag0[n0];
    if (n1 < n) a1v = ag0[n1];
  }
  f32x4 acc[8][2] = {};
#pragma unroll
  for (int ks = 0; ks < 4; ++ks) {
    int k0 = ks * 32 + lg * 8;
    bf16x8 nf0 = {}, nf1 = {};
    if (MODE == 1) {
      if (n0 < n) nf0 = *(const bf16x8*)&Abf[(size_t)n0 * 128 + k0];
      if (n1 < n) nf1 = *(const bf16x8*)&Abf[(size_t)n1 * 128 + k0];
      float4 pa = *(const float4*)&prm[k0];
      float4 pb = *(const float4*)&prm[k0 + 2];
      float4 pc = *(const float4*)&prm[k0 + 4];
      float4 pd = *(const float4*)&prm[k0 + 6];
      float scv[8] = {pa.x, pa.z, pb.x, pb.z, pc.x, pc.z, pd.x, pd.z};
      float ofv[8] = {pa.y, pa.w, pb.y, pb.w, pc.y, pc.w, pd.y, pd.w};
#pragma unroll
      for (int j = 0; j < 8; ++j) {
        float x0 = fmaxf(bf2f((unsigned short)nf0[j]) * scv[j] + ofv[j], 0.f);
        float x1 = fmaxf(bf2f((unsigned short)nf1[j]) * scv[j] + ofv[j], 0.f);
        nf0[j] = (short)f2bf(x0);
        nf1[j] = (short)f2bf(x1);
      }
    } else {   // MODE == 2: fused lin1+BN+ReLU from ag0
#pragma unroll
      for (int j = 0; j < 8; ++j) {
        int f = k0 + j;
        float4 wv = W1r[f];
        float2 p = prm[f];
        float x0 = (a0v.x * wv.x + a0v.y * wv.y + a0v.z * wv.z + wv.w) * p.x + p.y;
        float x1 = (a1v.x * wv.x + a1v.y * wv.y + a1v.z * wv.z + wv.w) * p.x + p.y;
        nf0[j] = (short)f2bf(fmaxf(x0, 0.f));
        nf1[j] = (short)f2bf(fmaxf(x1, 0.f));
      }
    }
#pragma unroll
    for (int NT = 0; NT < 8; ++NT) {
      bf16x8 wh = wfr[(NT * 4 + ks) * 64 + lane];
      bf16x8 wl = wfr[2048 + (NT * 4 + ks) * 64 + lane];
      acc[NT][0] = __builtin_amdgcn_mfma_f32_16x16x32_bf16(wh, nf0, acc[NT][0], 0, 0, 0);
      acc[NT][0] = __builtin_amdgcn_mfma_f32_16x16x32_bf16(wl, nf0, acc[NT][0], 0, 0, 0);
      acc[NT][1] = __builtin_amdgcn_mfma_f32_16x16x32_bf16(wh, nf1, acc[NT][1], 0, 0, 0);
      acc[NT][1] = __builtin_amdgcn_mfma_f32_16x16x32_bf16(wl, nf1, acc[NT][1], 0, 0, 0);
    }
  }
  float sc0 = (n0 < n) ? dinv[n0] : 0.f;
  float sc1 = (n1 < n) ? dinv[n1] : 0.f;
#pragma unroll
  for (int ng = 0; ng < 2; ++ng) {
    int node = (ng == 0) ? n0 : n1;
    float sc = (ng == 0) ? sc0 : sc1;
    if (node < n) {
#pragma unroll
      for (int NT = 0; NT < 8; ++NT) {
        ushort4 o;
        o.x = f2bf(acc[NT][ng][0] * sc);
        o.y = f2bf(acc[NT][ng][1] * sc);
        o.z = f2bf(acc[NT][ng][2] * sc);
        o.w = f2bf(acc[NT][ng][3] * sc);
        *(ushort4*)&C[(size_t)node * 128 + NT * 16 + lg * 4] = o;
      }
    }
  }
}

// ------- layer-2 aggregation: bf16 out + fused per-block BN partial stats -------
__global__ __launch_bounds__(256) void agg128_l2(const unsigned short* __restrict__ h,
                                                 const int* __restrict__ rp,
                                                 const int* __restrict__ csr,
                                                 const float* __restrict__ dinv,
                                                 const float* __restrict__ bias,
                                                 unsigned short* __restrict__ outb,
                                                 float* __restrict__ mpart, int n, int e,
                                                 int nagg) {
  int br = blockIdx.y;
  h += (size_t)br * n * 128;
  rp += (size_t)br * (n + 1);
  csr += (size_t)br * e;
  dinv += (size_t)br * n;
  outb += (size_t)br * n * 128;
  mpart += (size_t)br * nagg * 256;
  int t = threadIdx.x;
  int node = blockIdx.x * 16 + (t >> 4);
  int lane = t & 15;
  bool valid = node < n;
  const uint4* hp = (const uint4*)h;
  float acc[8] = {0.f};
  if (valid) {
    acc8(acc, hp[(size_t)node * 16 + lane]);
    int e0 = rp[node], e1 = rp[node + 1];
    int ee = e0;
    for (; ee + 8 <= e1; ee += 8) {
      int s0 = csr[ee],     s1 = csr[ee + 1], s2 = csr[ee + 2], s3 = csr[ee + 3];
      int s4 = csr[ee + 4], s5 = csr[ee + 5], s6 = csr[ee + 6], s7 = csr[ee + 7];
      uint4 v0 = hp[(size_t)s0 * 16 + lane];
      uint4 v1 = hp[(size_t)s1 * 16 + lane];
      uint4 v2 = hp[(size_t)s2 * 16 + lane];
      uint4 v3 = hp[(size_t)s3 * 16 + lane];
      uint4 v4 = hp[(size_t)s4 * 16 + lane];
      uint4 v5 = hp[(size_t)s5 * 16 + lane];
      uint4 v6 = hp[(size_t)s6 * 16 + lane];
      uint4 v7 = hp[(size_t)s7 * 16 + lane];
      acc8(acc, v0); acc8(acc, v1); acc8(acc, v2); acc8(acc, v3);
      acc8(acc, v4); acc8(acc, v5); acc8(acc, v6); acc8(acc, v7);
    }
    for (; ee + 4 <= e1; ee += 4) {
      int s0 = csr[ee], s1 = csr[ee + 1], s2 = csr[ee + 2], s3 = csr[ee + 3];
      uint4 v0 = hp[(size_t)s0 * 16 + lane];
      uint4 v1 = hp[(size_t)s1 * 16 + lane];
      uint4 v2 = hp[(size_t)s2 * 16 + lane];
      uint4 v3 = hp[(size_t)s3 * 16 + lane];
      acc8(acc, v0); acc8(acc, v1); acc8(acc, v2); acc8(acc, v3);
    }
    for (; ee < e1; ++ee) acc8(acc, hp[(size_t)csr[ee] * 16 + lane]);
  }
  float v[8], sq[8];
  if (valid) {
    float dd = dinv[node];
    float4 bb0 = *(const float4*)&bias[lane * 8];
    float4 bb1 = *(const float4*)&bias[lane * 8 + 4];
    v[0] = acc[0] * dd + bb0.x; v[1] = acc[1] * dd + bb0.y;
    v[2] = acc[2] * dd + bb0.z; v[3] = acc[3] * dd + bb0.w;
    v[4] = acc[4] * dd + bb1.x; v[5] = acc[5] * dd + bb1.y;
    v[6] = acc[6] * dd + bb1.z; v[7] = acc[7] * dd + bb1.w;
    uint4 o;
    o.x = pack2(v[0], v[1]); o.y = pack2(v[2], v[3]);
    o.z = pack2(v[4], v[5]); o.w = pack2(v[6], v[7]);
    *(uint4*)&outb[(size_t)node * 128 + lane * 8] = o;
  } else {
#pragma unroll
    for (int j = 0; j < 8; ++j) v[j] = 0.f;
  }
#pragma unroll
  for (int j = 0; j < 8; ++j) sq[j] = v[j] * v[j];
#pragma unroll
  for (int j = 0; j < 8; ++j) {
    v[j] += __shfl_xor(v[j], 16);  v[j] += __shfl_xor(v[j], 32);
    sq[j] += __shfl_xor(sq[j], 16); sq[j] += __shfl_xor(sq[j], 32);
  }
  __shared__ float sred[4][16][16];
  int wave = t >> 6, wl = t & 63;
  if (wl < 16) {
#pragma unroll
    for (int j = 0; j < 8; ++j) {
      sred[wave][wl][j] = v[j];
      sred[wave][wl][8 + j] = sq[j];
    }
  }
  __syncthreads();
  {
    int f = t & 127;
    int j = (f & 7) + ((t >> 7) << 3);   // 0-7 sum, 8-15 sumsq
    float s = sred[0][f >> 3][j] + sred[1][f >> 3][j]
            + sred[2][f >> 3][j] + sred[3][f >> 3][j];
    mpart[(size_t)blockIdx.x * 256 + t] = s;
  }
}

// stage-1 reduce of BN partials
__global__ __launch_bounds__(256) void bnred1(const float* __restrict__ mpart, int nblk,
                                              float* __restrict__ spart) {
  int br = blockIdx.y;
  mpart += (size_t)br * nblk * 256;
  spart += (size_t)br * 128 * 256;
  int t = threadIdx.x, b = blockIdx.x;
  float loc = 0.f;
  for (int i = b; i < nblk; i += 128) loc += mpart[(size_t)i * 256 + t];
  spart[b * 256 + t] = loc;
}

// stage-2: fold partials, compute per-feature (scale, offset)
__global__ void bnprep2(const float* __restrict__ spart,
                        const float* __restrict__ gam, const float* __restrict__ bet,
                        float invn, float2* __restrict__ prm) {
  int br = blockIdx.y;
  spart += (size_t)br * 128 * 256;
  prm += (size_t)br * 128;
  int t = threadIdx.x;
  float loc = 0.f;
  for (int i = 0; i < 128; ++i) loc += spart[i * 256 + t];
  __shared__ float sm[256];
  sm[t] = loc;
  __syncthreads();
  if (t < 128) {
    float mu = sm[t] * invn;
    float var = sm[128 + t] * invn - mu * mu;
    float sc = rsqrtf(fmaxf(var, 0.f) + 1e-5f) * gam[t];
    prm[t] = make_float2(sc, bet[t] - mu * sc);
  }
}

// ------- layer-3 aggregation with fused mean-pool accumulation ------------------
__global__ __launch_bounds__(256) void agg128_l3_pool(const unsigned short* __restrict__ h,
                                                      const int* __restrict__ rp,
                                                      const int* __restrict__ csr,
                                                      const float* __restrict__ dinv,
                                                      const float* __restrict__ bias,
                                                      const int* __restrict__ batch0,
                                                      const int* __restrict__ batch1,
                                                      float* __restrict__ pooled,
                                                      int n, int e, int g) {
  int br = blockIdx.y;
  h += (size_t)br * n * 128;
  rp += (size_t)br * (n + 1);
  csr += (size_t)br * e;
  dinv += (size_t)br * n;
  const int* batch = br ? batch1 : batch0;
  pooled += (size_t)br * g * 128;
  int t = threadIdx.x;
  int node = blockIdx.x * 16 + (t >> 4);
  int lane = t & 15;
  bool valid = node < n;
  const uint4* hp = (const uint4*)h;
  float acc[8] = {0.f};
  if (valid) {
    acc8(acc, hp[(size_t)node * 16 + lane]);
    int e0 = rp[node], e1 = rp[node + 1];
    int ee = e0;
    for (; ee + 8 <= e1; ee += 8) {
      int s0 = csr[ee],     s1 = csr[ee + 1], s2 = csr[ee + 2], s3 = csr[ee + 3];
      int s4 = csr[ee + 4], s5 = csr[ee + 5], s6 = csr[ee + 6], s7 = csr[ee + 7];
      uint4 v0 = hp[(size_t)s0 * 16 + lane];
      uint4 v1 = hp[(size_t)s1 * 16 + lane];
      uint4 v2 = hp[(size_t)s2 * 16 + lane];
      uint4 v3 = hp[(size_t)s3 * 16 + lane];
      uint4 v4 = hp[(size_t)s4 * 16 + lane];
      uint4 v5 = hp[(size_t)s5 * 16 + lane];
      uint4 v6 = hp[(size_t)s6 * 16 + lane];
      uint4 v7 = hp[(size_t)s7 * 16 + lane];
      acc8(acc, v0); acc8(acc, v1); acc8(acc, v2); acc8(acc, v3);
      acc8(acc, v4); acc8(acc, v5); acc8(acc, v6); acc8(acc, v7);
    }
    for (; ee + 4 <= e1; ee += 4) {
      int s0 = csr[ee], s1 = csr[ee + 1], s2 = csr[ee + 2], s3 = csr[ee + 3];
      uint4 v0 = hp[(size_t)s0 * 16 + lane];
      uint4 v1 = hp[(size_t)s1 * 16 + lane];
      uint4 v2 = hp[(size_t)s2 * 16 + lane];
      uint4 v3 = hp[(size_t)s3 * 16 + lane];
      acc8(acc, v0); acc8(acc, v1); acc8(acc, v2); acc8(acc, v3);
    }
    for (; ee < e1; ++ee) acc8(acc, hp[(size_t)csr[ee] * 16 + lane]);
  }
  __shared__ float lds[16][128];
  __shared__ int lgid[16];
  int ng = t >> 4;
  if (valid) {
    float dd = dinv[node];
    float4 bb0 = *(const float4*)&bias[lane * 8];
    float4 bb1 = *(const float4*)&bias[lane * 8 + 4];
    // bf16-round to match the precision the old path had (write+read bf16)
    float w0 = bf2f(f2bf(acc[0] * dd + bb0.x));
    float w1 = bf2f(f2bf(acc[1] * dd + bb0.y));
    float w2 = bf2f(f2bf(acc[2] * dd + bb0.z));
    float w3 = bf2f(f2bf(acc[3] * dd + bb0.w));
    float w4 = bf2f(f2bf(acc[4] * dd + bb1.x));
    float w5 = bf2f(f2bf(acc[5] * dd + bb1.y));
    float w6 = bf2f(f2bf(acc[6] * dd + bb1.z));
    float w7 = bf2f(f2bf(acc[7] * dd + bb1.w));
    lds[ng][lane * 8 + 0] = w0; lds[ng][lane * 8 + 1] = w1;
    lds[ng][lane * 8 + 2] = w2; lds[ng][lane * 8 + 3] = w3;
    lds[ng][lane * 8 + 4] = w4; lds[ng][lane * 8 + 5] = w5;
    lds[ng][lane * 8 + 6] = w6; lds[ng][lane * 8 + 7] = w7;
    if (lane == 0) lgid[ng] = batch[node];
  } else {
#pragma unroll
    for (int j = 0; j < 8; ++j) lds[ng][lane * 8 + j] = 0.f;
    if (lane == 0) lgid[ng] = -1;
  }
  __syncthreads();
  // per-feature run reduction over the block's 16 nodes (batch sorted -> runs)
  {
    int f = t & 127, half = t >> 7;
    int lo = half * 8, hi = lo + 8;
    float run = 0.f;
    int cur = lgid[lo];
    for (int k = lo; k < hi; ++k) {
      int gg = lgid[k];
      if (gg != cur) {
        if (cur >= 0 && run != 0.f) atomicAdd(&pooled[cur * 128 + f], run);
        run = 0.f;
        cur = gg;
      }
      run += lds[k][f];
    }
    if (cur >= 0 && run != 0.f) atomicAdd(&pooled[cur * 128 + f], run);
  }
}

// ---------------- MLP head + L2 normalize ----------------
__global__ void mlp_kernel(const float* __restrict__ pooled, const int* __restrict__ gstart,
                           const float* __restrict__ Wp1, const float* __restrict__ bp1,
                           const float* __restrict__ Wp2, const float* __restrict__ bp2,
                           float* __restrict__ out, int g) {
  int br = blockIdx.y;
  pooled += (size_t)br * g * 128;
  gstart += (size_t)br * (g + 1);
  out += (size_t)br * g * 512;
  int gg = blockIdx.x, t = threadIdx.x;
  __shared__ float pv[128], hid[128], ov[512], red[256];
  if (t < 128) {
    float cntf = (float)(gstart[gg + 1] - gstart[gg]);
    pv[t] = pooled[gg * 128 + t] / fmaxf(cntf, 1.0f);
  }
  __syncthreads();
  if (t < 128) {
    float a = bp1[t];
    for (int k = 0; k < 128; ++k) a += pv[k] * Wp1[k * 128 + t];
    hid[t] = fmaxf(a, 0.0f);
  }
  __syncthreads();
  for (int o = t; o < 512; o += 256) {
    float a = bp2[o];
    for (int k = 0; k < 128; ++k) a += hid[k] * Wp2[k * 512 + o];
    ov[o] = a;
  }
  __syncthreads();
  red[t] = ov[t] * ov[t] + ov[t + 256] * ov[t + 256];
  __syncthreads();
  for (int sdt = 128; sdt > 0; sdt >>= 1) {
    if (t < sdt) red[t] += red[t + sdt];
    __syncthreads();
  }
  float inv = 1.0f / fmaxf(sqrtf(red[0]), 1e-12f);
  for (int o = t; o < 512; o += 256) out[(size_t)gg * 512 + o] = ov[o] * inv;
}

// ---------------- host orchestration ----------------
extern "C" void kernel_launch(void* const* d_in, const int* in_sizes, int n_in,
                              void* d_out, int out_size, void* d_ws, size_t ws_size,
                              hipStream_t stream) {
  const int N = in_sizes[0] / 3;
  const int E = in_sizes[1] / 2;
  const int G = out_size / (2 * 512);
  const int NBUCK = (N + BUCKET_MASK) >> BUCKET_SHIFT;
  const int NB3 = (N + 255) / 256;
  const int NAGG = (N + 15) / 16;

  char* w = (char*)d_ws;
  auto alloc = [&](size_t bytes) -> void* {
    void* p = (void*)w;
    w += (bytes + 255) & ~(size_t)255;
    return p;
  };
  unsigned short* Abf      = (unsigned short*)alloc(2 * (size_t)N * 128 * 2);
  unsigned short* Bh       = (unsigned short*)alloc(2 * (size_t)N * 128 * 2);
  float*          dinv     = (float*)alloc(2 * (size_t)N * 4);
  float4*         xs       = (float4*)alloc(2 * (size_t)N * 16);
  float4*         ag0      = (float4*)alloc(2 * (size_t)N * 16);
  int*            rp       = (int*)alloc(2 * (size_t)(N + 1) * 4);
  int*            csr      = (int*)alloc(2 * (size_t)E * 4);
  int*            bucketed = (int*)alloc(2 * (size_t)E * 4);
  int*            bcnt     = (int*)alloc(2 * (size_t)NBUCK * 4);
  int*            bbase    = (int*)alloc(2 * (size_t)(NBUCK + 1) * 4);
  int*            bcur     = (int*)alloc(2 * (size_t)NBUCK * 4);
  int*            gstart   = (int*)alloc(2 * (size_t)(G + 1) * 4);
  float*          pooled   = (float*)alloc(2 * (size_t)G * 128 * 4);
  unsigned short* Wf2      = (unsigned short*)alloc(2 * 128 * 128 * 2);
  unsigned short* Wf3      = (unsigned short*)alloc(2 * 128 * 128 * 2);
  float*          mpart    = (float*)alloc(2 * (size_t)NB3 * 9 * 4);
  float*          mpart2   = (float*)alloc(2 * (size_t)NAGG * 256 * 4);
  float*          spart    = (float*)alloc(2 * (size_t)128 * 256 * 4);
  float4*         W1r      = (float4*)alloc(2 * 128 * 16);
  float2*         prm1     = (float2*)alloc(2 * 128 * 8);
  float2*         prm2     = (float2*)alloc(2 * 128 * 8);

  const float* x0    = (const float*)d_in[0];
  const int*   ei0   = (const int*)d_in[1];
  const int*   bat0  = (const int*)d_in[2];
  const float* x1    = (const float*)d_in[3];
  const int*   ei1   = (const int*)d_in[4];
  const int*   bat1  = (const int*)d_in[5];
  const float* W1  = (const float*)d_in[6];
  const float* b1  = (const float*)d_in[7];
  const float* W2  = (const float*)d_in[8];
  const float* b2  = (const float*)d_in[9];
  const float* W3  = (const float*)d_in[10];
  const float* b3  = (const float*)d_in[11];
  const float* g1  = (const float*)d_in[12];
  const float* be1 = (const float*)d_in[13];
  const float* g2  = (const float*)d_in[14];
  const float* be2 = (const float*)d_in[15];
  const float* Wp1 = (const float*)d_in[16];
  const float* bp1 = (const float*)d_in[17];
  const float* Wp2 = (const float*)d_in[18];
  const float* bp2 = (const float*)d_in[19];

  const int* src0 = ei0;
  const int* dst0 = ei0 + E;
  const int* src1 = ei1;
  const int* dst1 = ei1 + E;
  float* outp = (float*)d_out;

  const int TB = 256;
  const int NTILE = (E + TILE - 1) / TILE;
  const float invn = 1.0f / (float)N;

  wsplit2<<<dim3(64, 2), TB, 0, stream>>>(W2, W3, Wf2, Wf3);

  // CSR build (both branches batched)
  zero_u32<<<(2 * NBUCK + TB - 1) / TB, TB, 0, stream>>>((unsigned*)bcnt, 2 * NBUCK);
  bucket_count<<<dim3(256, 2), TB, 0, stream>>>(dst0, dst1, bcnt, E, NBUCK);
  bucket_scan<<<dim3(1, 2), 1024, 0, stream>>>(bcnt, bbase, bcur, NBUCK);
  bucket_scatter<<<dim3(NTILE, 2), TB, 0, stream>>>(src0, dst0, src1, dst1, bcur, bucketed, E, NBUCK);
  bucket_to_csr<<<dim3(NBUCK, 2), TB, 0, stream>>>(bucketed, bbase, rp, dinv, csr, N, E, NBUCK);

  graph_bounds<<<dim3((N + TB - 1) / TB, 2), TB, 0, stream>>>(bat0, bat1, gstart, N, G);

  // layer 1 (lin1 is fused into the layer-2 GEMM)
  xs_scale<<<dim3((N + TB - 1) / TB, 2), TB, 0, stream>>>(x0, x1, dinv, xs, N);
  agg_f3<<<dim3(NB3, 2), TB, 0, stream>>>(xs, rp, csr, dinv, ag0, mpart, N, E, NB3);
  bnprep1<<<dim3(1, 2), TB, 0, stream>>>(mpart, NB3, W1, b1, g1, be1, invn, W1r, prm1);

  // layer 2: gemm (fused lin1+BN1+ReLU from ag0) -> agg (bf16 out + BN stats)
  gemm_mfma_t<2><<<dim3((N + 127) / 128, 2), TB, 0, stream>>>(nullptr, ag0, W1r, Wf2, dinv, prm1, Bh, N);
  agg128_l2<<<dim3(NAGG, 2), TB, 0, stream>>>(Bh, rp, csr, dinv, b2, Abf, mpart2, N, E, NAGG);
  bnred1<<<dim3(128, 2), TB, 0, stream>>>(mpart2, NAGG, spart);
  bnprep2<<<dim3(1, 2), TB, 0, stream>>>(spart, g2, be2, invn, prm2);

  // layer 3: gemm with BN2+ReLU fused on load -> agg with fused mean-pool
  gemm_mfma_t<1><<<dim3((N + 127) / 128, 2), TB, 0, stream>>>(Abf, nullptr, nullptr, Wf3, dinv, prm2, Bh, N);
  zero_u32<<<(2 * G * 128 + TB - 1) / TB, TB, 0, stream>>>((unsigned*)pooled, 2 * G * 128);
  agg128_l3_pool<<<dim3(NAGG, 2), TB, 0, stream>>>(Bh, rp, csr, dinv, b3, bat0, bat1, pooled, N, E, G);

  // head
  mlp_kernel<<<dim3(G, 2), TB, 0, stream>>>(pooled, gstart, Wp1, bp1, Wp2, bp2, outp, G);
}